// Round 19
// baseline (974.111 us; speedup 1.0000x reference)
//
#include <hip/hip_runtime.h>
#include <cfloat>
#include <math.h>

#define NPTS 2048
#define R2   8192   // merged: 2 tensors x B=2 x N=2048
#define SPLITK 8

typedef __attribute__((ext_vector_type(8))) short bfrag;
typedef __attribute__((ext_vector_type(4))) float f32x4;

__device__ inline ushort f2bf(float f) {
  unsigned u = __float_as_uint(f);
  return (ushort)((u + 0x7fffu + ((u >> 16) & 1u)) >> 16);
}

// ---------------- fused prologue: prep_weights + transpose2 + knn (independent) ----------------
__global__ __launch_bounds__(256) void prologue(
    const float* __restrict__ conv1, const float* __restrict__ conv2,
    const float* __restrict__ a1w1, const float* __restrict__ a1w2,
    const float* __restrict__ a2w1, const float* __restrict__ a2w2,
    const float* __restrict__ gw2,
    const float* __restrict__ wk, const float* __restrict__ bk,
    const float* __restrict__ wv, const float* __restrict__ bv,
    float* __restrict__ dwA1, float* __restrict__ a1w2r,
    float* __restrict__ dwA2, float* __restrict__ a2w2r,
    float* __restrict__ gw2r, float* __restrict__ dwC1, float* __restrict__ dwC2,
    float* __restrict__ wkv, float* __restrict__ bkv,
    const float* __restrict__ in0, const float* __restrict__ in1, float* __restrict__ FT,
    const float* __restrict__ P0, const float* __restrict__ P1,
    int* __restrict__ idx, float* __restrict__ cosv)
{
  int bid = blockIdx.x, tid = threadIdx.x;
  if (bid < 256) {
    // ---- prep_weights body ----
    int i = bid * 256 + tid;
    if (i < 512*128) {
      int row = i >> 7, c = i & 127;
      float v1, v2;
      if (row < 128) {
        float s1 = 0.f, s2 = 0.f;
        for (int t = 0; t < 3; t++) {
          s1 += a1w1[(row*256 + c)*3 + t] - a1w1[(row*256 + 128 + c)*3 + t];
          s2 += a2w1[(row*256 + c)*3 + t] - a2w1[(row*256 + 128 + c)*3 + t];
        }
        v1 = s1; v2 = s2;
      } else {
        int t = (row - 128) >> 7, o = row & 127;
        v1 = a1w1[(o*256 + 128 + c)*3 + t];
        v2 = a2w1[(o*256 + 128 + c)*3 + t];
      }
      dwA1[i] = v1; dwA2[i] = v2;
      dwC2[i] = (row < 256) ? (conv2[row*256 + c] - conv2[row*256 + 128 + c])
                            : conv2[(row-256)*256 + 128 + c];
    }
    if (i < 128*384) {
      int o = i / 384, rem = i % 384, w = rem >> 7, c = rem & 127;
      a1w2r[i] = a1w2[(o*128 + c)*3 + w];
      a2w2r[i] = a2w2[(o*128 + c)*3 + w];
      gw2r[i]  = gw2[(o*128 + c)*3 + w];
    }
    if (i < 256*128) {
      int row = i >> 7, c = i & 127;
      dwC1[i] = (row < 128) ? (conv1[row*256 + c] - conv1[row*256 + 128 + c])
                            : conv1[(row-128)*256 + 128 + c];
      wkv[i] = (row < 128) ? wk[row*128 + c] : wv[(row-128)*128 + c];
    }
    if (i < 256) bkv[i] = (i < 128) ? bk[i] : bv[i - 128];
    return;
  }
  if (bid < 1280) {
    // ---- transpose2 body (I=128, J=2048) ----
    __shared__ float tile[32][33];
    int q = bid - 256;
    int zb = q >> 8, rem = q & 255, by = rem >> 6, bx = rem & 63;
    const float* src = (zb < 2) ? (in0 + (size_t)zb*128*2048) : (in1 + (size_t)(zb-2)*128*2048);
    float* dst = FT + (size_t)zb*2048*128;
    int i0 = by * 32, j0 = bx * 32;
    int tx = tid & 31, ty = tid >> 5;
    for (int s = 0; s < 32; s += 8)
      tile[ty + s][tx] = src[(size_t)(i0 + ty + s)*2048 + (j0 + tx)];
    __syncthreads();
    for (int s = 0; s < 32; s += 8)
      dst[(size_t)(j0 + ty + s)*128 + (i0 + tx)] = tile[tx][ty + s];
    return;
  }
  // ---- knn v5: tournament with incremental lane argmin ----
  {
    __shared__ float px[NPTS], py[NPTS], sq[NPTS];
    int gw = (bid - 1280) * 4 + (tid >> 6);
    int b4 = gw >> 11, n = gw & 2047;
    int lane = tid & 63;
    const float* Pb = (b4 < 2) ? (P0 + (size_t)b4 * 2 * NPTS) : (P1 + (size_t)(b4 - 2) * 2 * NPTS);
    for (int i = tid; i < NPTS; i += 256) {
      float x = Pb[i], y = Pb[NPTS + i];
      px[i] = x; py[i] = y;
      sq[i] = __fadd_rn(__fmul_rn(x, x), __fmul_rn(y, y));
    }
    __syncthreads();
    float xn = px[n], yn = py[n], sqn = sq[n];
    float d32[32];
#pragma unroll
    for (int j = 0; j < 32; j++) {
      int m = lane + j*64;
      float dot  = __fadd_rn(__fmul_rn(xn, px[m]), __fmul_rn(yn, py[m]));
      float dist = __fsub_rn(__fadd_rn(sqn, sq[m]), __fmul_rn(2.0f, dot));
      d32[j] = fmaxf(dist, 1e-12f);
    }
    // initial lane-local argmin
    float bv2 = d32[0]; int bj = 0;
#pragma unroll
    for (int j = 1; j < 32; j++) {
      bool lt = d32[j] < bv2;
      bv2 = lt ? d32[j] : bv2;
      bj = lt ? j : bj;
    }
    for (int r = 0; r < 10; r++) {
      float wvv = bv2;
      int   wii = lane + bj*64;
      for (int off = 32; off >= 1; off >>= 1) {
        float od = __shfl_xor(wvv, off);
        int   oi = __shfl_xor(wii, off);
        if (od < wvv || (od == wvv && oi < wii)) { wvv = od; wii = oi; }
      }
      if (r > 0 && lane == 0) {
        size_t base = (size_t)gw*9 + (r - 1);
        idx[base] = wii;
        float dot = __fadd_rn(__fmul_rn(xn, px[wii]), __fmul_rn(yn, py[wii]));
        cosv[base] = __fdiv_rn(dot, __fmul_rn(__fsqrt_rn(sqn), __fsqrt_rn(sq[wii])));
      }
      if ((wii & 63) == lane) {
        int wj = wii >> 6;
#pragma unroll
        for (int j = 0; j < 32; j++) if (j == wj) d32[j] = FLT_MAX;
        bv2 = d32[0]; bj = 0;
#pragma unroll
        for (int j = 1; j < 32; j++) {
          bool lt = d32[j] < bv2;
          bv2 = lt ? d32[j] : bv2;
          bj = lt ? j : bj;
        }
      }
    }
  }
}

// ---------------- transpose [b][I][J] -> [b][J][I] (final output, z=4) ----------------
__global__ void transpose_k(const float* __restrict__ in, float* __restrict__ out, int I, int J) {
  __shared__ float tile[32][33];
  int b = blockIdx.z;
  int i0 = blockIdx.y * 32, j0 = blockIdx.x * 32;
  int tx = threadIdx.x, ty = threadIdx.y;
  for (int s = 0; s < 32; s += 8)
    tile[ty + s][tx] = in[((size_t)b*I + (i0 + ty + s))*J + (j0 + tx)];
  __syncthreads();
  for (int s = 0; s < 32; s += 8)
    out[((size_t)b*J + (j0 + ty + s))*I + (i0 + tx)] = tile[tx][ty + s];
}

// ---------------- bf16-MFMA GEMM device body (optional fused stats-final tail) ----------------
template<int BM>
__device__ __forceinline__ void gemm_body(
    const float* __restrict__ p0, int w0, const float* __restrict__ st0, int a0, int xm0,
    const float* __restrict__ p1, int w1, const float* __restrict__ st1, int a1, int xm1,
    const float* __restrict__ p2, int w2, const float* __restrict__ st2, int a2, int xm2,
    const float* __restrict__ addp, const float* __restrict__ addst,
    const float* __restrict__ W, const float* __restrict__ bias,
    const float* __restrict__ resid,
    float* __restrict__ Y, int Cin, int O, int pack, float* __restrict__ Y2,
    float* __restrict__ part,
    int r0, int c0, int pbx,
    float* __restrict__ statout, int NB, int* __restrict__ ctr)
{
  __shared__ ushort Xs[BM][40];   // bf16, 80B row stride (16B-aligned frag reads)
  __shared__ ushort Ws[64][40];
  constexpr int RT = BM / 16;
  constexpr int XF = BM / 8;
  int tid = threadIdx.x;
  int wv = tid >> 6, l = tid & 63;
  int m16 = l & 15, kq = l >> 4;
  int sxr = tid & (BM - 1), sxc = (tid / BM) * XF;
  int swr = tid & 63, swc = (tid >> 6) * 8;
  f32x4 acc[RT];
#pragma unroll
  for (int t = 0; t < RT; t++) acc[t] = (f32x4){0.f, 0.f, 0.f, 0.f};
  for (int k0 = 0; k0 < Cin; k0 += 32) {
    {
      int r = r0 + sxr;
      int ac = k0 + sxc;
      const float* P; const float* st; int cc, lw, act, xm;
      if (ac < w0)            { P = p0; cc = ac;          lw = w0; st = st0; act = a0; xm = xm0; }
      else if (ac < w0 + w1)  { P = p1; cc = ac - w0;     lw = w1; st = st1; act = a1; xm = xm1; }
      else                    { P = p2; cc = ac - w0 - w1; lw = w2; st = st2; act = a2; xm = xm2; }
      float vv[XF];
#pragma unroll
      for (int q = 0; q < XF; q += 4)
        *(float4*)&vv[q] = *(const float4*)(P + (size_t)r*lw + cc + q);
      int b = r >> 11;
      if (st) {
#pragma unroll
        for (int j = 0; j < XF; j++) {
          int o = (cc + j) & (xm - 1);
          float m = st[(b*xm + o)*2], rs = st[(b*xm + o)*2 + 1];
          float v = (vv[j] - m) * rs;
          vv[j] = (act == 1) ? fmaxf(v, 0.f) : ((v >= 0.f) ? v : 0.2f*v);
        }
      }
      if (addp && ac >= 128) {
        int fc = (ac - 128) & 127;
        float av[XF];
#pragma unroll
        for (int q = 0; q < XF; q += 4)
          *(float4*)&av[q] = *(const float4*)(addp + (size_t)r*128 + fc + q);
        if (addst) {
#pragma unroll
          for (int j = 0; j < XF; j++) {
            int o = (fc + j) & 127;
            float m = addst[(b*128 + o)*2], rs = addst[(b*128 + o)*2 + 1];
            av[j] = fmaxf((av[j] - m) * rs, 0.f);
          }
        }
#pragma unroll
        for (int j = 0; j < XF; j++) vv[j] += av[j];
      }
      union { ushort u[XF]; ushort4 v4[XF/4]; } pk;
#pragma unroll
      for (int j = 0; j < XF; j++) pk.u[j] = f2bf(vv[j]);
#pragma unroll
      for (int q = 0; q < XF/4; q++) *(ushort4*)&Xs[sxr][sxc + q*4] = pk.v4[q];
    }
    {
      const float* s = W + (size_t)(c0 + swr)*Cin + k0 + swc;
      float4 v0 = *(const float4*)s, v1 = *(const float4*)(s + 4);
      union { ushort u[8]; ushort4 v4[2]; } pk;
      pk.u[0]=f2bf(v0.x); pk.u[1]=f2bf(v0.y); pk.u[2]=f2bf(v0.z); pk.u[3]=f2bf(v0.w);
      pk.u[4]=f2bf(v1.x); pk.u[5]=f2bf(v1.y); pk.u[6]=f2bf(v1.z); pk.u[7]=f2bf(v1.w);
      *(ushort4*)&Ws[swr][swc]     = pk.v4[0];
      *(ushort4*)&Ws[swr][swc + 4] = pk.v4[1];
    }
    __syncthreads();
    bfrag bf = *(const bfrag*)&Ws[wv*16 + m16][kq*8];
#pragma unroll
    for (int t = 0; t < RT; t++) {
      bfrag af = *(const bfrag*)&Xs[t*16 + m16][kq*8];
      acc[t] = __builtin_amdgcn_mfma_f32_16x16x32_bf16(af, bf, acc[t], 0, 0, 0);
    }
    __syncthreads();
  }
  int c = c0 + wv*16 + m16;
  float bi = bias ? bias[c] : 0.f;
  float ps = 0.f, ps2 = 0.f;
#pragma unroll
  for (int t = 0; t < RT; t++) {
#pragma unroll
    for (int i = 0; i < 4; i++) {
      int r = r0 + t*16 + kq*4 + i;
      float v = acc[t][i] + bi;
      if (resid) v += resid[(size_t)r*O + c];
      if (pack) {
        int cc2 = c & 127;
        int h = cc2 & 3, dd = cc2 >> 2, b = r >> 11, n = r & 2047;
        float* T = (pack == 1 || c < 128) ? Y : Y2;
        T[(((size_t)(b*4 + h))*NPTS + n)*32 + dd] = v;
      } else {
        Y[(size_t)r*O + c] = v;
      }
      ps += v; ps2 = fmaf(v, v, ps2);
    }
  }
  if (part) {
    ps  += __shfl_xor(ps, 16);  ps  += __shfl_xor(ps, 32);
    ps2 += __shfl_xor(ps2, 16); ps2 += __shfl_xor(ps2, 32);
    if (kq == 0) {
      part[((size_t)pbx*O + c)*2]     = ps;
      part[((size_t)pbx*O + c)*2 + 1] = ps2;
    }
    if (statout) {
      __threadfence();
      __syncthreads();
      __shared__ int lastBlk;
      if (tid == 0) lastBlk = (atomicAdd(ctr, 1) == (int)(gridDim.x*gridDim.y) - 1) ? 1 : 0;
      __syncthreads();
      if (!lastBlk) return;
      __threadfence();
      int nblk = (int)gridDim.x / NB;
      for (int p = tid; p < NB*O; p += 256) {
        int b = p / O, o = p % O;
        double S = 0.0, S2 = 0.0;
        for (int u = 0; u < nblk; u++) {
          size_t base = (((size_t)(b*nblk + u))*O + o)*2;
          S  += (double)part[base];
          S2 += (double)part[base + 1];
        }
        double mean = S / 2048;
        double var = S2 / 2048 - mean*mean;
        if (var < 0.0) var = 0.0;
        statout[p*2] = (float)mean;
        statout[p*2 + 1] = (float)(1.0 / sqrt(var + 1e-5));
      }
    }
  }
}

template<int BM>
__global__ __launch_bounds__(256) void gemm_m(
    const float* __restrict__ p0, int w0, const float* __restrict__ st0, int a0, int xm0,
    const float* __restrict__ p1, int w1, const float* __restrict__ st1, int a1, int xm1,
    const float* __restrict__ p2, int w2, const float* __restrict__ st2, int a2, int xm2,
    const float* __restrict__ addp, const float* __restrict__ addst,
    const float* __restrict__ W, const float* __restrict__ bias,
    const float* __restrict__ resid,
    float* __restrict__ Y, int Cin, int O, int pack, float* __restrict__ Y2,
    float* __restrict__ part, float* __restrict__ statout, int NB, int* __restrict__ ctr)
{
  gemm_body<BM>(p0,w0,st0,a0,xm0, p1,w1,st1,a1,xm1, p2,w2,st2,a2,xm2,
                addp,addst, W,bias,resid, Y,Cin,O,pack,Y2,part,
                blockIdx.x*BM, blockIdx.y*64, blockIdx.x, statout, NB, ctr);
}

// fused Q + KV projection: X rows [0..4095]=xin (Q), [4096..8191]=src (KV)
__global__ __launch_bounds__(256) void gemm_qkv(
    const float* __restrict__ Xbase,
    const float* __restrict__ wq, const float* __restrict__ bq, float* __restrict__ Qo,
    const float* __restrict__ wkv, const float* __restrict__ bkv, float* __restrict__ Ko,
    float* __restrict__ Vo)
{
  int bx = blockIdx.x, by = blockIdx.y;
  if (bx < 128) {
    if (by >= 2) return;
    gemm_body<32>(Xbase,128,nullptr,0,0, nullptr,0,nullptr,0,0, nullptr,0,nullptr,0,0,
                  nullptr,nullptr, wq, bq, nullptr, Qo, 128, 128, 1, nullptr, nullptr,
                  bx*32, by*64, 0, nullptr, 0, nullptr);
  } else {
    gemm_body<32>(Xbase + (size_t)4096*128,128,nullptr,0,0, nullptr,0,nullptr,0,0, nullptr,0,nullptr,0,0,
                  nullptr,nullptr, wkv, bkv, nullptr, Ko, 128, 256, 2, Vo, nullptr,
                  (bx-128)*32, by*64, 0, nullptr, 0, nullptr);
  }
}

// ---------------- annu conv1 combine: 4 rows/block + fused f64 stats partials ----------------
__global__ __launch_bounds__(256) void combine_annu(const float* __restrict__ GA, const int* __restrict__ idx,
                                                    const float* __restrict__ b1, float* __restrict__ A,
                                                    double* __restrict__ part) {
  int t = threadIdx.x;
  int o = t & 127, sub = t >> 7;
  int r0 = blockIdx.x * 4;
  __shared__ int nbs[4][9];
  if (t < 36) nbs[t / 9][t % 9] = idx[(size_t)(r0 + t/9)*9 + (t % 9)];
  __syncthreads();
  float bo = b1[o];
  double s = 0.0, s2 = 0.0;
  for (int rr = sub; rr < 4; rr += 2) {
    int r = r0 + rr, rb = r & ~2047;
    float ctr = GA[(size_t)r*512 + o] + bo;
#pragma unroll
    for (int w = 0; w < 3; w++) {
      float acc = ctr;
#pragma unroll
      for (int t3 = 0; t3 < 3; t3++) {
        int m = nbs[rr][w*3 + t3];
        acc += GA[(size_t)(rb + m)*512 + 128 + t3*128 + o];
      }
      A[(size_t)r*384 + w*128 + o] = acc;
      s += (double)acc; s2 += (double)acc * (double)acc;
    }
  }
  __shared__ double ls[256], ls2[256];
  ls[t] = s; ls2[t] = s2;
  __syncthreads();
  if (sub == 0) {
    s += ls[128 + o]; s2 += ls2[128 + o];
    part[((size_t)blockIdx.x*128 + o)*2] = s;
    part[((size_t)blockIdx.x*128 + o)*2 + 1] = s2;
  }
}

// ---------------- angle-feature conv1: 16 rows/block + fused f64 stats ----------------
__global__ __launch_bounds__(256) void cos_conv(const float* __restrict__ cosv, const float* __restrict__ gw1,
                                                const float* __restrict__ gb1, float* __restrict__ ANG,
                                                double* __restrict__ part) {
  int t = threadIdx.x;
  int o = t & 127, sub = t >> 7;
  int r0 = blockIdx.x * 16;
  float g0 = gw1[o*3], g1 = gw1[o*3+1], g2 = gw1[o*3+2], gb = gb1[o];
  __shared__ float cs[16][12];
  for (int i = t; i < 16*9; i += 256) cs[i / 9][i % 9] = cosv[(size_t)(r0 + i/9)*9 + (i % 9)];
  __syncthreads();
  double s = 0.0, s2 = 0.0;
  for (int rr = sub; rr < 16; rr += 2) {
    int r = r0 + rr;
#pragma unroll
    for (int w = 0; w < 3; w++) {
      float acc = gb;
      acc += cs[rr][w*3+0]*g0;
      acc += cs[rr][w*3+1]*g1;
      acc += cs[rr][w*3+2]*g2;
      ANG[(size_t)r*384 + w*128 + o] = acc;
      s += (double)acc; s2 += (double)acc * (double)acc;
    }
  }
  __shared__ double ls[256], ls2[256];
  ls[t] = s; ls2[t] = s2;
  __syncthreads();
  if (sub == 0) {
    s += ls[128 + o]; s2 += ls2[128 + o];
    part[((size_t)blockIdx.x*128 + o)*2] = s;
    part[((size_t)blockIdx.x*128 + o)*2 + 1] = s2;
  }
}

// ---------------- parallel stats final (f64 partials) ----------------
__global__ __launch_bounds__(256) void gm_final(const double* __restrict__ part, float* __restrict__ stats,
                                                int Cc, int NB, int nblk, int count) {
  int g = blockIdx.x * 8 + (threadIdx.x >> 5);
  int lane = threadIdx.x & 31;
  if (g >= NB*Cc) return;
  int b = g / Cc, o = g % Cc;
  double S = 0.0, S2 = 0.0;
  for (int u = lane; u < nblk; u += 32) {
    size_t blk = (size_t)(b*nblk + u);
    S  += part[(blk*Cc + o)*2];
    S2 += part[(blk*Cc + o)*2 + 1];
  }
  for (int off = 16; off >= 1; off >>= 1) {
    S  += __shfl_down(S, off, 32);
    S2 += __shfl_down(S2, off, 32);
  }
  if (lane == 0) {
    double mean = S / count;
    double var = S2 / count - mean*mean;
    if (var < 0.0) var = 0.0;
    stats[g*2] = (float)mean;
    stats[g*2 + 1] = (float)(1.0 / sqrt(var + 1e-5));
  }
}

// ---------------- gather + max over k + f64 partials (4 rows/block, idx in LDS) ----------------
__global__ __launch_bounds__(256) void gather_max_partial(const float* __restrict__ G, const int* __restrict__ idx,
                                                          float* __restrict__ maxbuf, double* __restrict__ part,
                                                          int Cc) {
  int t = threadIdx.x;
  int o = t % Cc, sub = t / Cc, nsub = 256 / Cc;
  int r0 = blockIdx.x * 4;
  __shared__ int nbs[4][9];
  if (t < 36) nbs[t / 9][t % 9] = idx[(size_t)(r0 + t/9)*9 + (t % 9)];
  __syncthreads();
  double s = 0.0, s2 = 0.0;
  for (int rr = sub; rr < 4; rr += nsub) {
    int r = r0 + rr, rb = r & ~2047;
    float g = G[(size_t)r*2*Cc + o];
    float mx = -3.4e38f;
#pragma unroll
    for (int k = 0; k < 9; k++) {
      int m = nbs[rr][k];
      float v = g + G[(size_t)(rb + m)*2*Cc + Cc + o];
      mx = fmaxf(mx, v); s += (double)v; s2 += (double)v*(double)v;
    }
    maxbuf[(size_t)r*Cc + o] = mx;
  }
  if (nsub == 2) {
    __shared__ double ls[256], ls2[256];
    ls[t] = s; ls2[t] = s2;
    __syncthreads();
    if (sub == 0) { s += ls[Cc + o]; s2 += ls2[Cc + o]; }
  }
  if (sub == 0) {
    part[((size_t)blockIdx.x*Cc + o)*2] = s;
    part[((size_t)blockIdx.x*Cc + o)*2 + 1] = s2;
  }
}

// ---------------- final: SA = lrelu(inorm(X3O)) + lrelu(inorm(X3A)) ----------------
__global__ void norm_add2(const float* __restrict__ src, float* __restrict__ dst,
                          const float* __restrict__ stats,
                          const float* __restrict__ addend, const float* __restrict__ astats,
                          int total) {
  int i = blockIdx.x * 256 + threadIdx.x;
  if (i >= total) return;
  int o = i & 127;
  int b = i >> 18;
  float m = stats[(b*128 + o)*2], rs = stats[(b*128 + o)*2 + 1];
  float v = (src[i] - m) * rs;
  v = (v >= 0.f) ? v : 0.2f*v;
  float ma = astats[(b*128 + o)*2], rsa = astats[(b*128 + o)*2 + 1];
  float a = (addend[i] - ma) * rsa;
  a = (a >= 0.f) ? a : 0.2f*a;
  dst[i] = v + a;
}

// ---------------- MFMA flash attention: 64 q-rows/block, split-K 8 (256 keys/part) ----------------
__global__ __launch_bounds__(256) void attn_part(const float* __restrict__ Qp, const float* __restrict__ Kp,
                                                 const float* __restrict__ Vp,
                                                 float* __restrict__ OP, float* __restrict__ ML) {
  __shared__ ushort Ks[64][40];   // K rows [key][dim], bf16
  __shared__ ushort Vt[32][72];   // V transposed [dim][key], bf16
  __shared__ ushort Pb[64][72];   // P rows [q-row][key 0..63], bf16 (front doubles as Q staging)
  int tid = threadIdx.x;
  int wv = tid >> 6, l = tid & 63;
  int d = l & 15, g = l >> 4;
  int kp = blockIdx.y, bh = blockIdx.z;
  int q0 = blockIdx.x * 64;
  const float* Qh = Qp + (size_t)bh * NPTS * 32;
  const float* Kh = Kp + (size_t)bh * NPTS * 32;
  const float* Vh = Vp + (size_t)bh * NPTS * 32;
  {
    int r = tid >> 2, c8 = (tid & 3) * 8;
    const float* q = Qh + (size_t)(q0 + r)*32 + c8;
    float4 v0 = *(const float4*)q, v1 = *(const float4*)(q + 4);
    union { ushort u[8]; ushort4 v4[2]; } pk;
    pk.u[0]=f2bf(v0.x); pk.u[1]=f2bf(v0.y); pk.u[2]=f2bf(v0.z); pk.u[3]=f2bf(v0.w);
    pk.u[4]=f2bf(v1.x); pk.u[5]=f2bf(v1.y); pk.u[6]=f2bf(v1.z); pk.u[7]=f2bf(v1.w);
    *(ushort4*)&Pb[r][c8]     = pk.v4[0];
    *(ushort4*)&Pb[r][c8 + 4] = pk.v4[1];
  }
  __syncthreads();
  bfrag qf = *(const bfrag*)&Pb[wv*16 + d][g*8];
  f32x4 Oc[2];
  Oc[0] = (f32x4){0.f,0.f,0.f,0.f}; Oc[1] = (f32x4){0.f,0.f,0.f,0.f};
  float m_[4] = {-FLT_MAX, -FLT_MAX, -FLT_MAX, -FLT_MAX};
  float l_[4] = {0.f, 0.f, 0.f, 0.f};
  const float sc = 0.17677669529663687f;   // 1/sqrt(32)
  int ks0 = kp * (NPTS / SPLITK);
  for (int k0 = ks0; k0 < ks0 + NPTS/SPLITK; k0 += 64) {
    __syncthreads();
    {
      int r = tid >> 2, c8 = (tid & 3) * 8;
      const float* kr = Kh + (size_t)(k0 + r)*32 + c8;
      float4 a0 = *(const float4*)kr, a1 = *(const float4*)(kr + 4);
      union { ushort u[8]; ushort4 v4[2]; } pk;
      pk.u[0]=f2bf(a0.x); pk.u[1]=f2bf(a0.y); pk.u[2]=f2bf(a0.z); pk.u[3]=f2bf(a0.w);
      pk.u[4]=f2bf(a1.x); pk.u[5]=f2bf(a1.y); pk.u[6]=f2bf(a1.z); pk.u[7]=f2bf(a1.w);
      *(ushort4*)&Ks[r][c8]     = pk.v4[0];
      *(ushort4*)&Ks[r][c8 + 4] = pk.v4[1];
      int vr = tid & 63, vd = (tid >> 6) * 8;
      const float* vp = Vh + (size_t)(k0 + vr)*32 + vd;
      float4 b0 = *(const float4*)vp, b1 = *(const float4*)(vp + 4);
      Vt[vd+0][vr] = f2bf(b0.x); Vt[vd+1][vr] = f2bf(b0.y);
      Vt[vd+2][vr] = f2bf(b0.z); Vt[vd+3][vr] = f2bf(b0.w);
      Vt[vd+4][vr] = f2bf(b1.x); Vt[vd+5][vr] = f2bf(b1.y);
      Vt[vd+6][vr] = f2bf(b1.z); Vt[vd+7][vr] = f2bf(b1.w);
    }
    __syncthreads();
    f32x4 S[4];
#pragma unroll
    for (int c = 0; c < 4; c++) {
      S[c] = (f32x4){0.f,0.f,0.f,0.f};
      bfrag kf = *(const bfrag*)&Ks[c*16 + d][g*8];
      S[c] = __builtin_amdgcn_mfma_f32_16x16x32_bf16(qf, kf, S[c], 0, 0, 0);
    }
    float cf[4];
#pragma unroll
    for (int i = 0; i < 4; i++) {
      float tm = fmaxf(fmaxf(S[0][i], S[1][i]), fmaxf(S[2][i], S[3][i])) * sc;
      for (int off = 1; off < 16; off <<= 1) tm = fmaxf(tm, __shfl_xor(tm, off));
      float mn = fmaxf(m_[i], tm);
      cf[i] = __expf(m_[i] - mn);
      m_[i] = mn;
    }
    float rs[4] = {0.f, 0.f, 0.f, 0.f};
    ushort pu[4][4];
#pragma unroll
    for (int c = 0; c < 4; c++)
#pragma unroll
      for (int i = 0; i < 4; i++) {
        float p = __expf(fmaf(S[c][i], sc, -m_[i]));
        rs[i] += p;
        pu[c][i] = f2bf(p);
      }
#pragma unroll
    for (int i = 0; i < 4; i++) {
      float r2 = rs[i];
      for (int off = 1; off < 16; off <<= 1) r2 += __shfl_xor(r2, off);
      l_[i] = l_[i]*cf[i] + r2;
      Oc[0][i] *= cf[i]; Oc[1][i] *= cf[i];
    }
#pragma unroll
    for (int c = 0; c < 4; c++)
#pragma unroll
      for (int i = 0; i < 4; i++)
        Pb[wv*16 + g*4 + i][c*16 + d] = pu[c][i];
#pragma unroll
    for (int s5 = 0; s5 < 2; s5++) {
      bfrag pf = *(const bfrag*)&Pb[wv*16 + d][g*8 + 32*s5];
#pragma unroll
      for (int td = 0; td < 2; td++) {
        union { ushort4 v4[2]; bfrag f; } vu;
        vu.v4[0] = *(const ushort4*)&Vt[td*16 + d][g*8 + 32*s5];
        vu.v4[1] = *(const ushort4*)&Vt[td*16 + d][g*8 + 32*s5 + 4];
        Oc[td] = __builtin_amdgcn_mfma_f32_16x16x32_bf16(pf, vu.f, Oc[td], 0, 0, 0);
      }
    }
  }
  size_t pb = (size_t)(kp*8 + bh) * NPTS;
#pragma unroll
  for (int i = 0; i < 4; i++) {
    int n = q0 + wv*16 + g*4 + i;
    OP[(pb + n)*32 + d]      = Oc[0][i];
    OP[(pb + n)*32 + 16 + d] = Oc[1][i];
    if (d == 0) { ML[(pb + n)*2] = m_[i]; ML[(pb + n)*2 + 1] = l_[i]; }
  }
}

// ---------------- merge the eight K-slices ----------------
__global__ void attn_merge(const float* __restrict__ OP, const float* __restrict__ ML,
                           float* __restrict__ out) {
  int i = blockIdx.x * 256 + threadIdx.x;   // 8*2048*16
  if (i >= 8*2048*16) return;
  int dp = (i & 15) * 2;
  int n  = (i >> 4) & 2047;
  int bh = i >> 15;
  float mv[SPLITK], lv[SPLITK];
  float mm = -FLT_MAX;
#pragma unroll
  for (int p = 0; p < SPLITK; p++) {
    size_t pp = ((size_t)(p*8 + bh) * NPTS + n);
    mv[p] = ML[pp*2]; lv[p] = ML[pp*2 + 1];
    mm = fmaxf(mm, mv[p]);
  }
  float L = 0.f, ox = 0.f, oy = 0.f;
#pragma unroll
  for (int p = 0; p < SPLITK; p++) {
    size_t pp = ((size_t)(p*8 + bh) * NPTS + n);
    float w = __expf(mv[p] - mm);
    L += w * lv[p];
    float2 o = *(const float2*)&OP[pp*32 + dp];
    ox += w * o.x; oy += w * o.y;
  }
  float inv = 1.f / L;
  int b = bh >> 2, h = bh & 3;
  out[((size_t)(b*NPTS + n))*128 + (dp+0)*4 + h] = ox * inv;
  out[((size_t)(b*NPTS + n))*128 + (dp+1)*4 + h] = oy * inv;
}

// ================= host =================
extern "C" void kernel_launch(void* const* d_in, const int* in_sizes, int n_in,
                              void* d_out, int out_size, void* d_ws, size_t ws_size,
                              hipStream_t stream) {
  (void)in_sizes; (void)n_in; (void)out_size; (void)ws_size;
  const float* desc0  = (const float*)d_in[0];
  const float* desc1  = (const float*)d_in[1];
  const float* coords0= (const float*)d_in[2];
  const float* coords1= (const float*)d_in[3];
  const float* conv1w = (const float*)d_in[4];
  const float* conv2w = (const float*)d_in[5];
  const float* conv3w = (const float*)d_in[6];
  const float* conv3ow= (const float*)d_in[7];
  const float* a1w1 = (const float*)d_in[8];
  const float* a1b1 = (const float*)d_in[9];
  const float* a1w2 = (const float*)d_in[10];
  const float* a1b2 = (const float*)d_in[11];
  const float* a2w1 = (const float*)d_in[12];
  const float* a2b1 = (const float*)d_in[13];
  const float* a2w2 = (const float*)d_in[14];
  const float* a2b2 = (const float*)d_in[15];
  const float* gw1  = (const float*)d_in[16];
  const float* gb1  = (const float*)d_in[17];
  const float* gw2  = (const float*)d_in[18];
  const float* gb2  = (const float*)d_in[19];
  const float* wq = (const float*)d_in[20]; const float* bq = (const float*)d_in[21];
  const float* wk = (const float*)d_in[22]; const float* bk = (const float*)d_in[23];
  const float* wv = (const float*)d_in[24]; const float* bv = (const float*)d_in[25];
  const float* wm = (const float*)d_in[26]; const float* bm = (const float*)d_in[27];
  const float* mw1 = (const float*)d_in[28]; const float* mb1 = (const float*)d_in[29];
  const float* mw2 = (const float*)d_in[30]; const float* mb2 = (const float*)d_in[31];

  float* ws = (float*)d_ws;
  size_t off = 0;
  auto alloc = [&](size_t nel) { size_t r = off; off += (nel + 63) & ~(size_t)63; return r; };
  float* DW_A1 = ws + alloc(512*128);
  float* W_A1R = ws + alloc(128*384);
  float* DW_A2 = ws + alloc(512*128);
  float* W_A2R = ws + alloc(128*384);
  float* W_G2R = ws + alloc(128*384);
  float* DW_C1 = ws + alloc(256*128);
  float* DW_C2 = ws + alloc(512*128);
  float* W_KV  = ws + alloc(256*128);
  float* B_KV  = ws + alloc(256);
  float* SA   = ws + alloc((size_t)R2*128);   // SA0 rows 0..4095 | SA1 rows 4096..8191
  float* XF0  = ws + alloc((size_t)4096*128); // contiguous with XF1 for fused z=4 transpose
  float* XF1  = ws + alloc((size_t)4096*128);
  int*   IDX  = (int*)(ws + alloc((size_t)R2*9));
  float* COSV = ws + alloc((size_t)R2*9);
  float* FT   = ws + alloc((size_t)R2*128);
  float* BIG  = ws + alloc((size_t)R2*512);
  float* ABUF = ws + alloc((size_t)R2*384);
  float* X1B  = ws + alloc((size_t)R2*128);
  float* FANG = ws + alloc((size_t)R2*128);
  float* X2B  = ws + alloc((size_t)R2*128);
  float* X3A  = ws + alloc((size_t)R2*128);
  float* X1O  = ws + alloc((size_t)R2*128);
  float* AB2  = ws + alloc((size_t)R2*256);
  float* X3O  = ws + alloc((size_t)R2*128);
  double* PART = (double*)(ws + alloc((size_t)2048*256*2*2));   // 1M doubles (8 MB)
  float*  PARTF = (float*)PART;                                  // aliased f32 partials
  float* STATS = ws + alloc(8*2048);
  float* MLB  = ws + alloc((size_t)SPLITK*8*NPTS*2);            // attn m/l partials
  int*   CTR  = (int*)(ws + alloc(64));
  float* ST_T   = STATS;
  float* ST_X1B = STATS + 2048;
  float* ST_FANG= STATS + 4096;
  float* ST_X2B = STATS + 6144;
  float* ST_X3A = STATS + 8192;
  float* ST_X1O = STATS + 10240;
  float* ST_AB  = STATS + 12288;
  float* ST_X3O = STATS + 14336;
  float* OP  = BIG;    // attn O partials: SPLITK*8*2048*32 = R2*512 floats exactly

  hipMemsetAsync(CTR, 0, 64*sizeof(int), stream);
  int ctr_id = 0;

  auto g64 = [&](const float* p0,int w0,const float* st0,int a0,int x0,
                 const float* p1,int w1,const float* st1,int a1,int x1,
                 const float* p2,int w2,const float* st2,int a2,int x2,
                 const float* addp,const float* addst,
                 const float* W,const float* bias,const float* resid,
                 float* Y,int R,int Cin,int O,int pack,float* Y2,float* part,float* statout) {
    gemm_m<64><<<dim3(R/64, O/64), 256, 0, stream>>>(p0,w0,st0,a0,x0, p1,w1,st1,a1,x1,
        p2,w2,st2,a2,x2, addp,addst, W,bias,resid, Y,Cin,O,pack,Y2,part,
        statout, R/2048, statout ? (CTR + ctr_id++) : nullptr);
  };
  auto g32 = [&](const float* p0,int w0,const float* st0,int a0,int x0,
                 const float* p1,int w1,const float* st1,int a1,int x1,
                 const float* p2,int w2,const float* st2,int a2,int x2,
                 const float* addp,const float* addst,
                 const float* W,const float* bias,const float* resid,
                 float* Y,int R,int Cin,int O,int pack,float* Y2,float* part,float* statout) {
    gemm_m<32><<<dim3(R/32, O/64), 256, 0, stream>>>(p0,w0,st0,a0,x0, p1,w1,st1,a1,x1,
        p2,w2,st2,a2,x2, addp,addst, W,bias,resid, Y,Cin,O,pack,Y2,part,
        statout, R/2048, statout ? (CTR + ctr_id++) : nullptr);
  };
  auto statsD = [&](float* stat, int O, int NB, int nblk, int count) {
    gm_final<<<(NB*O + 7)/8, 256, 0, stream>>>(PART, stat, O, NB, nblk, count);
  };
  auto gathermax = [&](const float* G, float* mx, int Cc, float* stat) {
    gather_max_partial<<<R2/4, 256, 0, stream>>>(G, IDX, mx, PART, Cc);
    statsD(stat, Cc, 4, 512, 2048*9);
  };

  // ===== fused prologue: prep_weights + transpose2 + knn =====
  prologue<<<3328, 256, 0, stream>>>(conv1w, conv2w, a1w1, a1w2, a2w1, a2w2, gw2,
                                     wk, bk, wv, bv,
                                     DW_A1, W_A1R, DW_A2, W_A2R, W_G2R, DW_C1, DW_C2,
                                     W_KV, B_KV,
                                     desc0, desc1, FT,
                                     coords0, coords1, IDX, COSV);

  // ===== merged branch section (both descs, R2 = 8192 rows, 4 instances) =====
  // annu1
  g64(FT,128,nullptr,0,0, nullptr,0,nullptr,0,0, nullptr,0,nullptr,0,0, nullptr,nullptr,
      DW_A1, nullptr, nullptr, BIG, R2, 128, 512, 0, nullptr, nullptr, nullptr);
  combine_annu<<<R2/4, 256, 0, stream>>>(BIG, IDX, a1b1, ABUF, PART);
  statsD(ST_T, 128, 4, 512, 2048*3);
  g32(ABUF,384,ST_T,1,128, nullptr,0,nullptr,0,0, nullptr,0,nullptr,0,0, nullptr,nullptr,
      W_A1R, a1b2, nullptr, X1B, R2, 384, 128, 0, nullptr, PARTF, ST_X1B);
  // f_ang (idx1 == idx2)
  cos_conv<<<R2/16, 256, 0, stream>>>(COSV, gw1, gb1, ABUF, PART);
  statsD(ST_T, 128, 4, 128, 2048*3);
  g32(ABUF,384,ST_T,1,128, nullptr,0,nullptr,0,0, nullptr,0,nullptr,0,0, nullptr,nullptr,
      W_G2R, gb2, nullptr, FANG, R2, 384, 128, 0, nullptr, PARTF, ST_FANG);
  // annu2 (X1B raw, normed in staging)
  g64(X1B,128,ST_X1B,1,128, nullptr,0,nullptr,0,0, nullptr,0,nullptr,0,0, nullptr,nullptr,
      DW_A2, nullptr, nullptr, BIG, R2, 128, 512, 0, nullptr, nullptr, nullptr);
  combine_annu<<<R2/4, 256, 0, stream>>>(BIG, IDX, a2b1, ABUF, PART);
  statsD(ST_T, 128, 4, 512, 2048*3);
  g32(ABUF,384,ST_T,1,128, nullptr,0,nullptr,0,0, nullptr,0,nullptr,0,0, nullptr,nullptr,
      W_A2R, a2b2, nullptr, X2B, R2, 384, 128, 0, nullptr, PARTF, ST_X2B);
  // x3 = conv3 @ [x0 | n(x1)+n(fang) | n(x2)+n(fang)]
  g32(FT,128,nullptr,0,0, X1B,128,ST_X1B,1,128, X2B,128,ST_X2B,1,128, FANG,ST_FANG,
      conv3w, nullptr, nullptr, X3A, R2, 384, 128, 0, nullptr, PARTF, ST_X3A);
  // x1o
  g64(FT,128,nullptr,0,0, nullptr,0,nullptr,0,0, nullptr,0,nullptr,0,0, nullptr,nullptr,
      DW_C1, nullptr, nullptr, BIG, R2, 128, 256, 0, nullptr, nullptr, nullptr);
  gathermax(BIG, X1O, 128, ST_X1O);
  // x2o (X1O = raw max, normed lrelu in staging)
  g64(X1O,128,ST_X1O,2,128, nullptr,0,nullptr,0,0, nullptr,0,nullptr,0,0, nullptr,nullptr,
      DW_C2, nullptr, nullptr, BIG, R2, 128, 512, 0, nullptr, nullptr, nullptr);
  gathermax(BIG, AB2, 256, ST_AB);
  // x3o = conv3o @ [x0 | n(x1o) | n(x2o)]
  g32(FT,128,nullptr,0,0, X1O,128,ST_X1O,2,128, AB2,256,ST_AB,2,256, nullptr,nullptr,
      conv3ow, nullptr, nullptr, X3O, R2, 512, 128, 0, nullptr, PARTF, ST_X3O);
  norm_add2<<<(R2*128 + 255)/256, 256, 0, stream>>>(X3O, SA, ST_X3O, X3A, ST_X3A, R2*128);

  // ===== cross-attention props (rows 4096 each) =====
  float* SA1 = SA + (size_t)4096*128;
  auto prop = [&](const float* xbase, float* dst) {
    const float* xin = xbase;
    gemm_qkv<<<dim3(256, 4), 256, 0, stream>>>(xbase, wq, bq, X1B, W_KV, B_KV, X2B, X3A);
    attn_part<<<dim3(2048/64, SPLITK, 8), 256, 0, stream>>>(X1B, X2B, X3A, OP, MLB);
    attn_merge<<<(8*2048*16 + 255)/256, 256, 0, stream>>>(OP, MLB, FANG);
    g32(FANG,128,nullptr,0,0, nullptr,0,nullptr,0,0, nullptr,0,nullptr,0,0, nullptr,nullptr,
        wm, bm, nullptr, X1O, 4096, 128, 128, 0, nullptr, nullptr, nullptr);
    g32(xin,128,nullptr,0,0, X1O,128,nullptr,0,0, nullptr,0,nullptr,0,0, nullptr,nullptr,
        mw1, mb1, nullptr, ABUF, 4096, 256, 256, 0, nullptr, PARTF, ST_T);
    g32(ABUF,256,ST_T,1,256, nullptr,0,nullptr,0,0, nullptr,0,nullptr,0,0, nullptr,nullptr,
        mw2, mb2, xin, dst, 4096, 256, 128, 0, nullptr, nullptr, nullptr);
  };

  prop(SA, XF0);
  prop(SA1, XF1);

  transpose_k<<<dim3(128/32, 2048/32, 4), dim3(32, 8), 0, stream>>>(XF0, (float*)d_out, 2048, 128);
}

// Round 20
// 468.654 us; speedup vs baseline: 2.0785x; 2.0785x over previous
//
#include <hip/hip_runtime.h>
#include <cfloat>
#include <math.h>

#define NPTS 2048
#define R2   8192   // merged: 2 tensors x B=2 x N=2048
#define SPLITK 8

typedef __attribute__((ext_vector_type(8))) short bfrag;
typedef __attribute__((ext_vector_type(4))) float f32x4;

__device__ inline ushort f2bf(float f) {
  unsigned u = __float_as_uint(f);
  return (ushort)((u + 0x7fffu + ((u >> 16) & 1u)) >> 16);
}

// ---------------- fused prologue: prep_weights + transpose2 + knn (independent) ----------------
__global__ __launch_bounds__(256) void prologue(
    const float* __restrict__ conv1, const float* __restrict__ conv2,
    const float* __restrict__ a1w1, const float* __restrict__ a1w2,
    const float* __restrict__ a2w1, const float* __restrict__ a2w2,
    const float* __restrict__ gw2,
    const float* __restrict__ wk, const float* __restrict__ bk,
    const float* __restrict__ wv, const float* __restrict__ bv,
    float* __restrict__ dwA1, float* __restrict__ a1w2r,
    float* __restrict__ dwA2, float* __restrict__ a2w2r,
    float* __restrict__ gw2r, float* __restrict__ dwC1, float* __restrict__ dwC2,
    float* __restrict__ wkv, float* __restrict__ bkv,
    const float* __restrict__ in0, const float* __restrict__ in1, float* __restrict__ FT,
    const float* __restrict__ P0, const float* __restrict__ P1,
    int* __restrict__ idx, float* __restrict__ cosv)
{
  int bid = blockIdx.x, tid = threadIdx.x;
  if (bid < 256) {
    // ---- prep_weights body ----
    int i = bid * 256 + tid;
    if (i < 512*128) {
      int row = i >> 7, c = i & 127;
      float v1, v2;
      if (row < 128) {
        float s1 = 0.f, s2 = 0.f;
        for (int t = 0; t < 3; t++) {
          s1 += a1w1[(row*256 + c)*3 + t] - a1w1[(row*256 + 128 + c)*3 + t];
          s2 += a2w1[(row*256 + c)*3 + t] - a2w1[(row*256 + 128 + c)*3 + t];
        }
        v1 = s1; v2 = s2;
      } else {
        int t = (row - 128) >> 7, o = row & 127;
        v1 = a1w1[(o*256 + 128 + c)*3 + t];
        v2 = a2w1[(o*256 + 128 + c)*3 + t];
      }
      dwA1[i] = v1; dwA2[i] = v2;
      dwC2[i] = (row < 256) ? (conv2[row*256 + c] - conv2[row*256 + 128 + c])
                            : conv2[(row-256)*256 + 128 + c];
    }
    if (i < 128*384) {
      int o = i / 384, rem = i % 384, w = rem >> 7, c = rem & 127;
      a1w2r[i] = a1w2[(o*128 + c)*3 + w];
      a2w2r[i] = a2w2[(o*128 + c)*3 + w];
      gw2r[i]  = gw2[(o*128 + c)*3 + w];
    }
    if (i < 256*128) {
      int row = i >> 7, c = i & 127;
      dwC1[i] = (row < 128) ? (conv1[row*256 + c] - conv1[row*256 + 128 + c])
                            : conv1[(row-128)*256 + 128 + c];
      wkv[i] = (row < 128) ? wk[row*128 + c] : wv[(row-128)*128 + c];
    }
    if (i < 256) bkv[i] = (i < 128) ? bk[i] : bv[i - 128];
    return;
  }
  if (bid < 1280) {
    // ---- transpose2 body (I=128, J=2048) ----
    __shared__ float tile[32][33];
    int q = bid - 256;
    int zb = q >> 8, rem = q & 255, by = rem >> 6, bx = rem & 63;
    const float* src = (zb < 2) ? (in0 + (size_t)zb*128*2048) : (in1 + (size_t)(zb-2)*128*2048);
    float* dst = FT + (size_t)zb*2048*128;
    int i0 = by * 32, j0 = bx * 32;
    int tx = tid & 31, ty = tid >> 5;
    for (int s = 0; s < 32; s += 8)
      tile[ty + s][tx] = src[(size_t)(i0 + ty + s)*2048 + (j0 + tx)];
    __syncthreads();
    for (int s = 0; s < 32; s += 8)
      dst[(size_t)(j0 + ty + s)*128 + (i0 + tx)] = tile[tx][ty + s];
    return;
  }
  // ---- knn v5: tournament with incremental lane argmin (exact lex order) ----
  {
    __shared__ float px[NPTS], py[NPTS], sq[NPTS];
    int gw = (bid - 1280) * 4 + (tid >> 6);
    int b4 = gw >> 11, n = gw & 2047;
    int lane = tid & 63;
    const float* Pb = (b4 < 2) ? (P0 + (size_t)b4 * 2 * NPTS) : (P1 + (size_t)(b4 - 2) * 2 * NPTS);
    for (int i = tid; i < NPTS; i += 256) {
      float x = Pb[i], y = Pb[NPTS + i];
      px[i] = x; py[i] = y;
      sq[i] = __fadd_rn(__fmul_rn(x, x), __fmul_rn(y, y));
    }
    __syncthreads();
    float xn = px[n], yn = py[n], sqn = sq[n];
    float d32[32];
#pragma unroll
    for (int j = 0; j < 32; j++) {
      int m = lane + j*64;
      float dot  = __fadd_rn(__fmul_rn(xn, px[m]), __fmul_rn(yn, py[m]));
      float dist = __fsub_rn(__fadd_rn(sqn, sq[m]), __fmul_rn(2.0f, dot));
      d32[j] = fmaxf(dist, 1e-12f);
    }
    float bv2 = d32[0]; int bj = 0;
#pragma unroll
    for (int j = 1; j < 32; j++) {
      bool lt = d32[j] < bv2;
      bv2 = lt ? d32[j] : bv2;
      bj = lt ? j : bj;
    }
    for (int r = 0; r < 10; r++) {
      float wvv = bv2;
      int   wii = lane + bj*64;
      for (int off = 32; off >= 1; off >>= 1) {
        float od = __shfl_xor(wvv, off);
        int   oi = __shfl_xor(wii, off);
        if (od < wvv || (od == wvv && oi < wii)) { wvv = od; wii = oi; }
      }
      if (r > 0 && lane == 0) {
        size_t base = (size_t)gw*9 + (r - 1);
        idx[base] = wii;
        float dot = __fadd_rn(__fmul_rn(xn, px[wii]), __fmul_rn(yn, py[wii]));
        cosv[base] = __fdiv_rn(dot, __fmul_rn(__fsqrt_rn(sqn), __fsqrt_rn(sq[wii])));
      }
      if ((wii & 63) == lane) {
        int wj = wii >> 6;
#pragma unroll
        for (int j = 0; j < 32; j++) if (j == wj) d32[j] = FLT_MAX;
        bv2 = d32[0]; bj = 0;
#pragma unroll
        for (int j = 1; j < 32; j++) {
          bool lt = d32[j] < bv2;
          bv2 = lt ? d32[j] : bv2;
          bj = lt ? j : bj;
        }
      }
    }
  }
}

// ---------------- transpose [b][I][J] -> [b][J][I] (final output, z=4) ----------------
__global__ void transpose_k(const float* __restrict__ in, float* __restrict__ out, int I, int J) {
  __shared__ float tile[32][33];
  int b = blockIdx.z;
  int i0 = blockIdx.y * 32, j0 = blockIdx.x * 32;
  int tx = threadIdx.x, ty = threadIdx.y;
  for (int s = 0; s < 32; s += 8)
    tile[ty + s][tx] = in[((size_t)b*I + (i0 + ty + s))*J + (j0 + tx)];
  __syncthreads();
  for (int s = 0; s < 32; s += 8)
    out[((size_t)b*J + (j0 + ty + s))*I + (i0 + tx)] = tile[tx][ty + s];
}

// ---------------- bf16-MFMA GEMM device body ----------------
template<int BM>
__device__ __forceinline__ void gemm_body(
    const float* __restrict__ p0, int w0, const float* __restrict__ st0, int a0, int xm0,
    const float* __restrict__ p1, int w1, const float* __restrict__ st1, int a1, int xm1,
    const float* __restrict__ p2, int w2, const float* __restrict__ st2, int a2, int xm2,
    const float* __restrict__ addp, const float* __restrict__ addst,
    const float* __restrict__ W, const float* __restrict__ bias,
    const float* __restrict__ resid,
    float* __restrict__ Y, int Cin, int O, int pack, float* __restrict__ Y2,
    float* __restrict__ part,
    int r0, int c0, int pbx)
{
  __shared__ ushort Xs[BM][40];   // bf16, 80B row stride (16B-aligned frag reads)
  __shared__ ushort Ws[64][40];
  constexpr int RT = BM / 16;
  constexpr int XF = BM / 8;
  int tid = threadIdx.x;
  int wv = tid >> 6, l = tid & 63;
  int m16 = l & 15, kq = l >> 4;
  int sxr = tid & (BM - 1), sxc = (tid / BM) * XF;
  int swr = tid & 63, swc = (tid >> 6) * 8;
  f32x4 acc[RT];
#pragma unroll
  for (int t = 0; t < RT; t++) acc[t] = (f32x4){0.f, 0.f, 0.f, 0.f};
  for (int k0 = 0; k0 < Cin; k0 += 32) {
    {
      int r = r0 + sxr;
      int ac = k0 + sxc;
      const float* P; const float* st; int cc, lw, act, xm;
      if (ac < w0)            { P = p0; cc = ac;          lw = w0; st = st0; act = a0; xm = xm0; }
      else if (ac < w0 + w1)  { P = p1; cc = ac - w0;     lw = w1; st = st1; act = a1; xm = xm1; }
      else                    { P = p2; cc = ac - w0 - w1; lw = w2; st = st2; act = a2; xm = xm2; }
      float vv[XF];
#pragma unroll
      for (int q = 0; q < XF; q += 4)
        *(float4*)&vv[q] = *(const float4*)(P + (size_t)r*lw + cc + q);
      int b = r >> 11;
      if (st) {
#pragma unroll
        for (int j = 0; j < XF; j++) {
          int o = (cc + j) & (xm - 1);
          float m = st[(b*xm + o)*2], rs = st[(b*xm + o)*2 + 1];
          float v = (vv[j] - m) * rs;
          vv[j] = (act == 1) ? fmaxf(v, 0.f) : ((v >= 0.f) ? v : 0.2f*v);
        }
      }
      if (addp && ac >= 128) {
        int fc = (ac - 128) & 127;
        float av[XF];
#pragma unroll
        for (int q = 0; q < XF; q += 4)
          *(float4*)&av[q] = *(const float4*)(addp + (size_t)r*128 + fc + q);
        if (addst) {
#pragma unroll
          for (int j = 0; j < XF; j++) {
            int o = (fc + j) & 127;
            float m = addst[(b*128 + o)*2], rs = addst[(b*128 + o)*2 + 1];
            av[j] = fmaxf((av[j] - m) * rs, 0.f);
          }
        }
#pragma unroll
        for (int j = 0; j < XF; j++) vv[j] += av[j];
      }
      union { ushort u[XF]; ushort4 v4[XF/4]; } pk;
#pragma unroll
      for (int j = 0; j < XF; j++) pk.u[j] = f2bf(vv[j]);
#pragma unroll
      for (int q = 0; q < XF/4; q++) *(ushort4*)&Xs[sxr][sxc + q*4] = pk.v4[q];
    }
    {
      const float* s = W + (size_t)(c0 + swr)*Cin + k0 + swc;
      float4 v0 = *(const float4*)s, v1 = *(const float4*)(s + 4);
      union { ushort u[8]; ushort4 v4[2]; } pk;
      pk.u[0]=f2bf(v0.x); pk.u[1]=f2bf(v0.y); pk.u[2]=f2bf(v0.z); pk.u[3]=f2bf(v0.w);
      pk.u[4]=f2bf(v1.x); pk.u[5]=f2bf(v1.y); pk.u[6]=f2bf(v1.z); pk.u[7]=f2bf(v1.w);
      *(ushort4*)&Ws[swr][swc]     = pk.v4[0];
      *(ushort4*)&Ws[swr][swc + 4] = pk.v4[1];
    }
    __syncthreads();
    bfrag bf = *(const bfrag*)&Ws[wv*16 + m16][kq*8];
#pragma unroll
    for (int t = 0; t < RT; t++) {
      bfrag af = *(const bfrag*)&Xs[t*16 + m16][kq*8];
      acc[t] = __builtin_amdgcn_mfma_f32_16x16x32_bf16(af, bf, acc[t], 0, 0, 0);
    }
    __syncthreads();
  }
  int c = c0 + wv*16 + m16;
  float bi = bias ? bias[c] : 0.f;
  float ps = 0.f, ps2 = 0.f;
#pragma unroll
  for (int t = 0; t < RT; t++) {
#pragma unroll
    for (int i = 0; i < 4; i++) {
      int r = r0 + t*16 + kq*4 + i;
      float v = acc[t][i] + bi;
      if (resid) v += resid[(size_t)r*O + c];
      if (pack) {
        int cc2 = c & 127;
        int h = cc2 & 3, dd = cc2 >> 2, b = r >> 11, n = r & 2047;
        float* T = (pack == 1 || c < 128) ? Y : Y2;
        T[(((size_t)(b*4 + h))*NPTS + n)*32 + dd] = v;
      } else {
        Y[(size_t)r*O + c] = v;
      }
      ps += v; ps2 = fmaf(v, v, ps2);
    }
  }
  if (part) {
    ps  += __shfl_xor(ps, 16);  ps  += __shfl_xor(ps, 32);
    ps2 += __shfl_xor(ps2, 16); ps2 += __shfl_xor(ps2, 32);
    if (kq == 0) {
      part[((size_t)pbx*O + c)*2]     = ps;
      part[((size_t)pbx*O + c)*2 + 1] = ps2;
    }
  }
}

template<int BM>
__global__ __launch_bounds__(256) void gemm_m(
    const float* __restrict__ p0, int w0, const float* __restrict__ st0, int a0, int xm0,
    const float* __restrict__ p1, int w1, const float* __restrict__ st1, int a1, int xm1,
    const float* __restrict__ p2, int w2, const float* __restrict__ st2, int a2, int xm2,
    const float* __restrict__ addp, const float* __restrict__ addst,
    const float* __restrict__ W, const float* __restrict__ bias,
    const float* __restrict__ resid,
    float* __restrict__ Y, int Cin, int O, int pack, float* __restrict__ Y2,
    float* __restrict__ part)
{
  gemm_body<BM>(p0,w0,st0,a0,xm0, p1,w1,st1,a1,xm1, p2,w2,st2,a2,xm2,
                addp,addst, W,bias,resid, Y,Cin,O,pack,Y2,part,
                blockIdx.x*BM, blockIdx.y*64, blockIdx.x);
}

// fused Q + KV projection: X rows [0..4095]=xin (Q), [4096..8191]=src (KV)
__global__ __launch_bounds__(256) void gemm_qkv(
    const float* __restrict__ Xbase,
    const float* __restrict__ wq, const float* __restrict__ bq, float* __restrict__ Qo,
    const float* __restrict__ wkv, const float* __restrict__ bkv, float* __restrict__ Ko,
    float* __restrict__ Vo)
{
  int bx = blockIdx.x, by = blockIdx.y;
  if (bx < 128) {
    if (by >= 2) return;
    gemm_body<32>(Xbase,128,nullptr,0,0, nullptr,0,nullptr,0,0, nullptr,0,nullptr,0,0,
                  nullptr,nullptr, wq, bq, nullptr, Qo, 128, 128, 1, nullptr, nullptr,
                  bx*32, by*64, 0);
  } else {
    gemm_body<32>(Xbase + (size_t)4096*128,128,nullptr,0,0, nullptr,0,nullptr,0,0, nullptr,0,nullptr,0,0,
                  nullptr,nullptr, wkv, bkv, nullptr, Ko, 128, 256, 2, Vo, nullptr,
                  (bx-128)*32, by*64, 0);
  }
}

// ---------------- annu conv1 combine: 4 rows/block + fused f64 stats partials ----------------
__global__ __launch_bounds__(256) void combine_annu(const float* __restrict__ GA, const int* __restrict__ idx,
                                                    const float* __restrict__ b1, float* __restrict__ A,
                                                    double* __restrict__ part) {
  int t = threadIdx.x;
  int o = t & 127, sub = t >> 7;
  int r0 = blockIdx.x * 4;
  __shared__ int nbs[4][9];
  if (t < 36) nbs[t / 9][t % 9] = idx[(size_t)(r0 + t/9)*9 + (t % 9)];
  __syncthreads();
  float bo = b1[o];
  double s = 0.0, s2 = 0.0;
  for (int rr = sub; rr < 4; rr += 2) {
    int r = r0 + rr, rb = r & ~2047;
    float ctr = GA[(size_t)r*512 + o] + bo;
#pragma unroll
    for (int w = 0; w < 3; w++) {
      float acc = ctr;
#pragma unroll
      for (int t3 = 0; t3 < 3; t3++) {
        int m = nbs[rr][w*3 + t3];
        acc += GA[(size_t)(rb + m)*512 + 128 + t3*128 + o];
      }
      A[(size_t)r*384 + w*128 + o] = acc;
      s += (double)acc; s2 += (double)acc * (double)acc;
    }
  }
  __shared__ double ls[256], ls2[256];
  ls[t] = s; ls2[t] = s2;
  __syncthreads();
  if (sub == 0) {
    s += ls[128 + o]; s2 += ls2[128 + o];
    part[((size_t)blockIdx.x*128 + o)*2] = s;
    part[((size_t)blockIdx.x*128 + o)*2 + 1] = s2;
  }
}

// ---------------- fused: gm_final_f(ST_X1B) || cos_conv (disjoint partial regions) ----------------
__global__ __launch_bounds__(256) void stats_cos(const float* __restrict__ partf, float* __restrict__ stat,
                                                 const float* __restrict__ cosv, const float* __restrict__ gw1,
                                                 const float* __restrict__ gb1, float* __restrict__ ANG,
                                                 double* __restrict__ part2) {
  int bid = blockIdx.x, t = threadIdx.x;
  if (bid < 64) {
    // gm_final_f body: Cc=128, NB=4, nblk=64, count=2048
    int g = bid * 8 + (t >> 5);
    int lane = t & 31;
    if (g >= 512) return;
    int b = g >> 7, o = g & 127;
    double S = 0.0, S2 = 0.0;
    for (int u = lane; u < 64; u += 32) {
      size_t blk = (size_t)(b*64 + u);
      S  += (double)partf[(blk*128 + o)*2];
      S2 += (double)partf[(blk*128 + o)*2 + 1];
    }
    for (int off = 16; off >= 1; off >>= 1) {
      S  += __shfl_down(S, off, 32);
      S2 += __shfl_down(S2, off, 32);
    }
    if (lane == 0) {
      double mean = S / 2048;
      double var = S2 / 2048 - mean*mean;
      if (var < 0.0) var = 0.0;
      stat[g*2] = (float)mean;
      stat[g*2 + 1] = (float)(1.0 / sqrt(var + 1e-5));
    }
    return;
  }
  // cos_conv body (writes part2)
  {
    int cbid = bid - 64;
    int o = t & 127, sub = t >> 7;
    int r0 = cbid * 16;
    float g0 = gw1[o*3], g1 = gw1[o*3+1], g2 = gw1[o*3+2], gb = gb1[o];
    __shared__ float cs[16][12];
    for (int i = t; i < 16*9; i += 256) cs[i / 9][i % 9] = cosv[(size_t)(r0 + i/9)*9 + (i % 9)];
    __syncthreads();
    double s = 0.0, s2 = 0.0;
    for (int rr = sub; rr < 16; rr += 2) {
      int r = r0 + rr;
#pragma unroll
      for (int w = 0; w < 3; w++) {
        float acc = gb;
        acc += cs[rr][w*3+0]*g0;
        acc += cs[rr][w*3+1]*g1;
        acc += cs[rr][w*3+2]*g2;
        ANG[(size_t)r*384 + w*128 + o] = acc;
        s += (double)acc; s2 += (double)acc * (double)acc;
      }
    }
    __shared__ double ls[256], ls2[256];
    ls[t] = s; ls2[t] = s2;
    __syncthreads();
    if (sub == 0) {
      s += ls[128 + o]; s2 += ls2[128 + o];
      part2[((size_t)cbid*128 + o)*2] = s;
      part2[((size_t)cbid*128 + o)*2 + 1] = s2;
    }
  }
}

// ---------------- parallel stats final (f64 partials) ----------------
__global__ __launch_bounds__(256) void gm_final(const double* __restrict__ part, float* __restrict__ stats,
                                                int Cc, int NB, int nblk, int count) {
  int g = blockIdx.x * 8 + (threadIdx.x >> 5);
  int lane = threadIdx.x & 31;
  if (g >= NB*Cc) return;
  int b = g / Cc, o = g % Cc;
  double S = 0.0, S2 = 0.0;
  for (int u = lane; u < nblk; u += 32) {
    size_t blk = (size_t)(b*nblk + u);
    S  += part[(blk*Cc + o)*2];
    S2 += part[(blk*Cc + o)*2 + 1];
  }
  for (int off = 16; off >= 1; off >>= 1) {
    S  += __shfl_down(S, off, 32);
    S2 += __shfl_down(S2, off, 32);
  }
  if (lane == 0) {
    double mean = S / count;
    double var = S2 / count - mean*mean;
    if (var < 0.0) var = 0.0;
    stats[g*2] = (float)mean;
    stats[g*2 + 1] = (float)(1.0 / sqrt(var + 1e-5));
  }
}

// ---------------- parallel stats final (f32 partials, f64 accumulate) ----------------
__global__ __launch_bounds__(256) void gm_final_f(const float* __restrict__ part, float* __restrict__ stats,
                                                  int Cc, int NB, int nblk, int count) {
  int g = blockIdx.x * 8 + (threadIdx.x >> 5);
  int lane = threadIdx.x & 31;
  if (g >= NB*Cc) return;
  int b = g / Cc, o = g % Cc;
  double S = 0.0, S2 = 0.0;
  for (int u = lane; u < nblk; u += 32) {
    size_t blk = (size_t)(b*nblk + u);
    S  += (double)part[(blk*Cc + o)*2];
    S2 += (double)part[(blk*Cc + o)*2 + 1];
  }
  for (int off = 16; off >= 1; off >>= 1) {
    S  += __shfl_down(S, off, 32);
    S2 += __shfl_down(S2, off, 32);
  }
  if (lane == 0) {
    double mean = S / count;
    double var = S2 / count - mean*mean;
    if (var < 0.0) var = 0.0;
    stats[g*2] = (float)mean;
    stats[g*2 + 1] = (float)(1.0 / sqrt(var + 1e-5));
  }
}

// ---------------- gather + max over k + f64 partials (4 rows/block, idx in LDS) ----------------
__global__ __launch_bounds__(256) void gather_max_partial(const float* __restrict__ G, const int* __restrict__ idx,
                                                          float* __restrict__ maxbuf, double* __restrict__ part,
                                                          int Cc) {
  int t = threadIdx.x;
  int o = t % Cc, sub = t / Cc, nsub = 256 / Cc;
  int r0 = blockIdx.x * 4;
  __shared__ int nbs[4][9];
  if (t < 36) nbs[t / 9][t % 9] = idx[(size_t)(r0 + t/9)*9 + (t % 9)];
  __syncthreads();
  double s = 0.0, s2 = 0.0;
  for (int rr = sub; rr < 4; rr += nsub) {
    int r = r0 + rr, rb = r & ~2047;
    float g = G[(size_t)r*2*Cc + o];
    float mx = -3.4e38f;
#pragma unroll
    for (int k = 0; k < 9; k++) {
      int m = nbs[rr][k];
      float v = g + G[(size_t)(rb + m)*2*Cc + Cc + o];
      mx = fmaxf(mx, v); s += (double)v; s2 += (double)v*(double)v;
    }
    maxbuf[(size_t)r*Cc + o] = mx;
  }
  if (nsub == 2) {
    __shared__ double ls[256], ls2[256];
    ls[t] = s; ls2[t] = s2;
    __syncthreads();
    if (sub == 0) { s += ls[Cc + o]; s2 += ls2[Cc + o]; }
  }
  if (sub == 0) {
    part[((size_t)blockIdx.x*Cc + o)*2] = s;
    part[((size_t)blockIdx.x*Cc + o)*2 + 1] = s2;
  }
}

// ---------------- final: SA = lrelu(inorm(X3O)) + lrelu(inorm(X3A)) ----------------
__global__ void norm_add2(const float* __restrict__ src, float* __restrict__ dst,
                          const float* __restrict__ stats,
                          const float* __restrict__ addend, const float* __restrict__ astats,
                          int total) {
  int i = blockIdx.x * 256 + threadIdx.x;
  if (i >= total) return;
  int o = i & 127;
  int b = i >> 18;
  float m = stats[(b*128 + o)*2], rs = stats[(b*128 + o)*2 + 1];
  float v = (src[i] - m) * rs;
  v = (v >= 0.f) ? v : 0.2f*v;
  float ma = astats[(b*128 + o)*2], rsa = astats[(b*128 + o)*2 + 1];
  float a = (addend[i] - ma) * rsa;
  a = (a >= 0.f) ? a : 0.2f*a;
  dst[i] = v + a;
}

// ---------------- MFMA flash attention: 64 q-rows/block, split-K 8 (256 keys/part) ----------------
__global__ __launch_bounds__(256) void attn_part(const float* __restrict__ Qp, const float* __restrict__ Kp,
                                                 const float* __restrict__ Vp,
                                                 float* __restrict__ OP, float* __restrict__ ML) {
  __shared__ ushort Ks[64][40];   // K rows [key][dim], bf16
  __shared__ ushort Vt[32][72];   // V transposed [dim][key], bf16
  __shared__ ushort Pb[64][72];   // P rows [q-row][key 0..63], bf16 (front doubles as Q staging)
  int tid = threadIdx.x;
  int wv = tid >> 6, l = tid & 63;
  int d = l & 15, g = l >> 4;
  int kp = blockIdx.y, bh = blockIdx.z;
  int q0 = blockIdx.x * 64;
  const float* Qh = Qp + (size_t)bh * NPTS * 32;
  const float* Kh = Kp + (size_t)bh * NPTS * 32;
  const float* Vh = Vp + (size_t)bh * NPTS * 32;
  {
    int r = tid >> 2, c8 = (tid & 3) * 8;
    const float* q = Qh + (size_t)(q0 + r)*32 + c8;
    float4 v0 = *(const float4*)q, v1 = *(const float4*)(q + 4);
    union { ushort u[8]; ushort4 v4[2]; } pk;
    pk.u[0]=f2bf(v0.x); pk.u[1]=f2bf(v0.y); pk.u[2]=f2bf(v0.z); pk.u[3]=f2bf(v0.w);
    pk.u[4]=f2bf(v1.x); pk.u[5]=f2bf(v1.y); pk.u[6]=f2bf(v1.z); pk.u[7]=f2bf(v1.w);
    *(ushort4*)&Pb[r][c8]     = pk.v4[0];
    *(ushort4*)&Pb[r][c8 + 4] = pk.v4[1];
  }
  __syncthreads();
  bfrag qf = *(const bfrag*)&Pb[wv*16 + d][g*8];
  f32x4 Oc[2];
  Oc[0] = (f32x4){0.f,0.f,0.f,0.f}; Oc[1] = (f32x4){0.f,0.f,0.f,0.f};
  float m_[4] = {-FLT_MAX, -FLT_MAX, -FLT_MAX, -FLT_MAX};
  float l_[4] = {0.f, 0.f, 0.f, 0.f};
  const float sc = 0.17677669529663687f;   // 1/sqrt(32)
  int ks0 = kp * (NPTS / SPLITK);
  for (int k0 = ks0; k0 < ks0 + NPTS/SPLITK; k0 += 64) {
    __syncthreads();
    {
      int r = tid >> 2, c8 = (tid & 3) * 8;
      const float* kr = Kh + (size_t)(k0 + r)*32 + c8;
      float4 a0 = *(const float4*)kr, a1 = *(const float4*)(kr + 4);
      union { ushort u[8]; ushort4 v4[2]; } pk;
      pk.u[0]=f2bf(a0.x); pk.u[1]=f2bf(a0.y); pk.u[2]=f2bf(a0.z); pk.u[3]=f2bf(a0.w);
      pk.u[4]=f2bf(a1.x); pk.u[5]=f2bf(a1.y); pk.u[6]=f2bf(a1.z); pk.u[7]=f2bf(a1.w);
      *(ushort4*)&Ks[r][c8]     = pk.v4[0];
      *(ushort4*)&Ks[r][c8 + 4] = pk.v4[1];
      int vr = tid & 63, vd = (tid >> 6) * 8;
      const float* vp = Vh + (size_t)(k0 + vr)*32 + vd;
      float4 b0 = *(const float4*)vp, b1 = *(const float4*)(vp + 4);
      Vt[vd+0][vr] = f2bf(b0.x); Vt[vd+1][vr] = f2bf(b0.y);
      Vt[vd+2][vr] = f2bf(b0.z); Vt[vd+3][vr] = f2bf(b0.w);
      Vt[vd+4][vr] = f2bf(b1.x); Vt[vd+5][vr] = f2bf(b1.y);
      Vt[vd+6][vr] = f2bf(b1.z); Vt[vd+7][vr] = f2bf(b1.w);
    }
    __syncthreads();
    f32x4 S[4];
#pragma unroll
    for (int c = 0; c < 4; c++) {
      S[c] = (f32x4){0.f,0.f,0.f,0.f};
      bfrag kf = *(const bfrag*)&Ks[c*16 + d][g*8];
      S[c] = __builtin_amdgcn_mfma_f32_16x16x32_bf16(qf, kf, S[c], 0, 0, 0);
    }
    float cf[4];
#pragma unroll
    for (int i = 0; i < 4; i++) {
      float tm = fmaxf(fmaxf(S[0][i], S[1][i]), fmaxf(S[2][i], S[3][i])) * sc;
      for (int off = 1; off < 16; off <<= 1) tm = fmaxf(tm, __shfl_xor(tm, off));
      float mn = fmaxf(m_[i], tm);
      cf[i] = __expf(m_[i] - mn);
      m_[i] = mn;
    }
    float rs[4] = {0.f, 0.f, 0.f, 0.f};
    ushort pu[4][4];
#pragma unroll
    for (int c = 0; c < 4; c++)
#pragma unroll
      for (int i = 0; i < 4; i++) {
        float p = __expf(fmaf(S[c][i], sc, -m_[i]));
        rs[i] += p;
        pu[c][i] = f2bf(p);
      }
#pragma unroll
    for (int i = 0; i < 4; i++) {
      float r2 = rs[i];
      for (int off = 1; off < 16; off <<= 1) r2 += __shfl_xor(r2, off);
      l_[i] = l_[i]*cf[i] + r2;
      Oc[0][i] *= cf[i]; Oc[1][i] *= cf[i];
    }
#pragma unroll
    for (int c = 0; c < 4; c++)
#pragma unroll
      for (int i = 0; i < 4; i++)
        Pb[wv*16 + g*4 + i][c*16 + d] = pu[c][i];
#pragma unroll
    for (int s5 = 0; s5 < 2; s5++) {
      bfrag pf = *(const bfrag*)&Pb[wv*16 + d][g*8 + 32*s5];
#pragma unroll
      for (int td = 0; td < 2; td++) {
        union { ushort4 v4[2]; bfrag f; } vu;
        vu.v4[0] = *(const ushort4*)&Vt[td*16 + d][g*8 + 32*s5];
        vu.v4[1] = *(const ushort4*)&Vt[td*16 + d][g*8 + 32*s5 + 4];
        Oc[td] = __builtin_amdgcn_mfma_f32_16x16x32_bf16(pf, vu.f, Oc[td], 0, 0, 0);
      }
    }
  }
  size_t pb = (size_t)(kp*8 + bh) * NPTS;
#pragma unroll
  for (int i = 0; i < 4; i++) {
    int n = q0 + wv*16 + g*4 + i;
    OP[(pb + n)*32 + d]      = Oc[0][i];
    OP[(pb + n)*32 + 16 + d] = Oc[1][i];
    if (d == 0) { ML[(pb + n)*2] = m_[i]; ML[(pb + n)*2 + 1] = l_[i]; }
  }
}

// ---------------- merge the eight K-slices ----------------
__global__ void attn_merge(const float* __restrict__ OP, const float* __restrict__ ML,
                           float* __restrict__ out) {
  int i = blockIdx.x * 256 + threadIdx.x;   // 8*2048*16
  if (i >= 8*2048*16) return;
  int dp = (i & 15) * 2;
  int n  = (i >> 4) & 2047;
  int bh = i >> 15;
  float mv[SPLITK], lv[SPLITK];
  float mm = -FLT_MAX;
#pragma unroll
  for (int p = 0; p < SPLITK; p++) {
    size_t pp = ((size_t)(p*8 + bh) * NPTS + n);
    mv[p] = ML[pp*2]; lv[p] = ML[pp*2 + 1];
    mm = fmaxf(mm, mv[p]);
  }
  float L = 0.f, ox = 0.f, oy = 0.f;
#pragma unroll
  for (int p = 0; p < SPLITK; p++) {
    size_t pp = ((size_t)(p*8 + bh) * NPTS + n);
    float w = __expf(mv[p] - mm);
    L += w * lv[p];
    float2 o = *(const float2*)&OP[pp*32 + dp];
    ox += w * o.x; oy += w * o.y;
  }
  float inv = 1.f / L;
  int b = bh >> 2, h = bh & 3;
  out[((size_t)(b*NPTS + n))*128 + (dp+0)*4 + h] = ox * inv;
  out[((size_t)(b*NPTS + n))*128 + (dp+1)*4 + h] = oy * inv;
}

// ================= host =================
extern "C" void kernel_launch(void* const* d_in, const int* in_sizes, int n_in,
                              void* d_out, int out_size, void* d_ws, size_t ws_size,
                              hipStream_t stream) {
  (void)in_sizes; (void)n_in; (void)out_size; (void)ws_size;
  const float* desc0  = (const float*)d_in[0];
  const float* desc1  = (const float*)d_in[1];
  const float* coords0= (const float*)d_in[2];
  const float* coords1= (const float*)d_in[3];
  const float* conv1w = (const float*)d_in[4];
  const float* conv2w = (const float*)d_in[5];
  const float* conv3w = (const float*)d_in[6];
  const float* conv3ow= (const float*)d_in[7];
  const float* a1w1 = (const float*)d_in[8];
  const float* a1b1 = (const float*)d_in[9];
  const float* a1w2 = (const float*)d_in[10];
  const float* a1b2 = (const float*)d_in[11];
  const float* a2w1 = (const float*)d_in[12];
  const float* a2b1 = (const float*)d_in[13];
  const float* a2w2 = (const float*)d_in[14];
  const float* a2b2 = (const float*)d_in[15];
  const float* gw1  = (const float*)d_in[16];
  const float* gb1  = (const float*)d_in[17];
  const float* gw2  = (const float*)d_in[18];
  const float* gb2  = (const float*)d_in[19];
  const float* wq = (const float*)d_in[20]; const float* bq = (const float*)d_in[21];
  const float* wk = (const float*)d_in[22]; const float* bk = (const float*)d_in[23];
  const float* wv = (const float*)d_in[24]; const float* bv = (const float*)d_in[25];
  const float* wm = (const float*)d_in[26]; const float* bm = (const float*)d_in[27];
  const float* mw1 = (const float*)d_in[28]; const float* mb1 = (const float*)d_in[29];
  const float* mw2 = (const float*)d_in[30]; const float* mb2 = (const float*)d_in[31];

  float* ws = (float*)d_ws;
  size_t off = 0;
  auto alloc = [&](size_t nel) { size_t r = off; off += (nel + 63) & ~(size_t)63; return r; };
  float* DW_A1 = ws + alloc(512*128);
  float* W_A1R = ws + alloc(128*384);
  float* DW_A2 = ws + alloc(512*128);
  float* W_A2R = ws + alloc(128*384);
  float* W_G2R = ws + alloc(128*384);
  float* DW_C1 = ws + alloc(256*128);
  float* DW_C2 = ws + alloc(512*128);
  float* W_KV  = ws + alloc(256*128);
  float* B_KV  = ws + alloc(256);
  float* SA   = ws + alloc((size_t)R2*128);   // SA0 rows 0..4095 | SA1 rows 4096..8191
  float* XF0  = ws + alloc((size_t)4096*128); // contiguous with XF1 for fused z=4 transpose
  float* XF1  = ws + alloc((size_t)4096*128);
  int*   IDX  = (int*)(ws + alloc((size_t)R2*9));
  float* COSV = ws + alloc((size_t)R2*9);
  float* FT   = ws + alloc((size_t)R2*128);
  float* BIG  = ws + alloc((size_t)R2*512);
  float* ABUF = ws + alloc((size_t)R2*384);
  float* X1B  = ws + alloc((size_t)R2*128);
  float* FANG = ws + alloc((size_t)R2*128);
  float* X2B  = ws + alloc((size_t)R2*128);
  float* X3A  = ws + alloc((size_t)R2*128);
  float* X1O  = ws + alloc((size_t)R2*128);
  float* AB2  = ws + alloc((size_t)R2*256);
  float* X3O  = ws + alloc((size_t)R2*128);
  double* PART = (double*)(ws + alloc((size_t)2048*256*2*2));   // 1M doubles (8 MB)
  float*  PARTF = (float*)PART;                                  // aliased f32 partials
  double* PART2 = PART + (size_t)512*1024;                       // disjoint region for cos stats
  float* STATS = ws + alloc(8*2048);
  float* MLB  = ws + alloc((size_t)SPLITK*8*NPTS*2);            // attn m/l partials
  float* ST_T   = STATS;
  float* ST_X1B = STATS + 2048;
  float* ST_FANG= STATS + 4096;
  float* ST_X2B = STATS + 6144;
  float* ST_X3A = STATS + 8192;
  float* ST_X1O = STATS + 10240;
  float* ST_AB  = STATS + 12288;
  float* ST_X3O = STATS + 14336;
  float* OP  = BIG;    // attn O partials: SPLITK*8*2048*32 = R2*512 floats exactly

  auto g64 = [&](const float* p0,int w0,const float* st0,int a0,int x0,
                 const float* p1,int w1,const float* st1,int a1,int x1,
                 const float* p2,int w2,const float* st2,int a2,int x2,
                 const float* addp,const float* addst,
                 const float* W,const float* bias,const float* resid,
                 float* Y,int R,int Cin,int O,int pack,float* Y2,float* part) {
    gemm_m<64><<<dim3(R/64, O/64), 256, 0, stream>>>(p0,w0,st0,a0,x0, p1,w1,st1,a1,x1,
        p2,w2,st2,a2,x2, addp,addst, W,bias,resid, Y,Cin,O,pack,Y2,part);
  };
  auto g32 = [&](const float* p0,int w0,const float* st0,int a0,int x0,
                 const float* p1,int w1,const float* st1,int a1,int x1,
                 const float* p2,int w2,const float* st2,int a2,int x2,
                 const float* addp,const float* addst,
                 const float* W,const float* bias,const float* resid,
                 float* Y,int R,int Cin,int O,int pack,float* Y2,float* part) {
    gemm_m<32><<<dim3(R/32, O/64), 256, 0, stream>>>(p0,w0,st0,a0,x0, p1,w1,st1,a1,x1,
        p2,w2,st2,a2,x2, addp,addst, W,bias,resid, Y,Cin,O,pack,Y2,part);
  };
  auto statsF = [&](float* stat, int O, int NB, int nblk, int count) {
    gm_final_f<<<(NB*O + 7)/8, 256, 0, stream>>>(PARTF, stat, O, NB, nblk, count);
  };
  auto statsD = [&](float* stat, int O, int NB, int nblk, int count) {
    gm_final<<<(NB*O + 7)/8, 256, 0, stream>>>(PART, stat, O, NB, nblk, count);
  };
  auto gathermax = [&](const float* G, float* mx, int Cc, float* stat) {
    gather_max_partial<<<R2/4, 256, 0, stream>>>(G, IDX, mx, PART, Cc);
    statsD(stat, Cc, 4, 512, 2048*9);
  };

  // ===== fused prologue: prep_weights + transpose2 + knn =====
  prologue<<<3328, 256, 0, stream>>>(conv1w, conv2w, a1w1, a1w2, a2w1, a2w2, gw2,
                                     wk, bk, wv, bv,
                                     DW_A1, W_A1R, DW_A2, W_A2R, W_G2R, DW_C1, DW_C2,
                                     W_KV, B_KV,
                                     desc0, desc1, FT,
                                     coords0, coords1, IDX, COSV);

  // ===== merged branch section (both descs, R2 = 8192 rows, 4 instances) =====
  // annu1
  g64(FT,128,nullptr,0,0, nullptr,0,nullptr,0,0, nullptr,0,nullptr,0,0, nullptr,nullptr,
      DW_A1, nullptr, nullptr, BIG, R2, 128, 512, 0, nullptr, nullptr);
  combine_annu<<<R2/4, 256, 0, stream>>>(BIG, IDX, a1b1, ABUF, PART);
  statsD(ST_T, 128, 4, 512, 2048*3);
  g32(ABUF,384,ST_T,1,128, nullptr,0,nullptr,0,0, nullptr,0,nullptr,0,0, nullptr,nullptr,
      W_A1R, a1b2, nullptr, X1B, R2, 384, 128, 0, nullptr, PARTF);
  // fused: statsF(ST_X1B) || cos_conv (f_ang conv1; writes PART2)
  stats_cos<<<64 + R2/16, 256, 0, stream>>>(PARTF, ST_X1B, COSV, gw1, gb1, ABUF, PART2);
  gm_final<<<(4*128 + 7)/8, 256, 0, stream>>>(PART2, ST_T, 128, 4, 128, 2048*3);
  g32(ABUF,384,ST_T,1,128, nullptr,0,nullptr,0,0, nullptr,0,nullptr,0,0, nullptr,nullptr,
      W_G2R, gb2, nullptr, FANG, R2, 384, 128, 0, nullptr, PARTF);
  statsF(ST_FANG, 128, 4, 64, 2048);
  // annu2 (X1B raw, normed in staging)
  g64(X1B,128,ST_X1B,1,128, nullptr,0,nullptr,0,0, nullptr,0,nullptr,0,0, nullptr,nullptr,
      DW_A2, nullptr, nullptr, BIG, R2, 128, 512, 0, nullptr, nullptr);
  combine_annu<<<R2/4, 256, 0, stream>>>(BIG, IDX, a2b1, ABUF, PART);
  statsD(ST_T, 128, 4, 512, 2048*3);
  g32(ABUF,384,ST_T,1,128, nullptr,0,nullptr,0,0, nullptr,0,nullptr,0,0, nullptr,nullptr,
      W_A2R, a2b2, nullptr, X2B, R2, 384, 128, 0, nullptr, PARTF);
  statsF(ST_X2B, 128, 4, 64, 2048);
  // x3 = conv3 @ [x0 | n(x1)+n(fang) | n(x2)+n(fang)]
  g32(FT,128,nullptr,0,0, X1B,128,ST_X1B,1,128, X2B,128,ST_X2B,1,128, FANG,ST_FANG,
      conv3w, nullptr, nullptr, X3A, R2, 384, 128, 0, nullptr, PARTF);
  statsF(ST_X3A, 128, 4, 64, 2048);
  // x1o
  g64(FT,128,nullptr,0,0, nullptr,0,nullptr,0,0, nullptr,0,nullptr,0,0, nullptr,nullptr,
      DW_C1, nullptr, nullptr, BIG, R2, 128, 256, 0, nullptr, nullptr);
  gathermax(BIG, X1O, 128, ST_X1O);
  // x2o (X1O = raw max, normed lrelu in staging)
  g64(X1O,128,ST_X1O,2,128, nullptr,0,nullptr,0,0, nullptr,0,nullptr,0,0, nullptr,nullptr,
      DW_C2, nullptr, nullptr, BIG, R2, 128, 512, 0, nullptr, nullptr);
  gathermax(BIG, AB2, 256, ST_AB);
  // x3o = conv3o @ [x0 | n(x1o) | n(x2o)]
  g32(FT,128,nullptr,0,0, X1O,128,ST_X1O,2,128, AB2,256,ST_AB,2,256, nullptr,nullptr,
      conv3ow, nullptr, nullptr, X3O, R2, 512, 128, 0, nullptr, PARTF);
  statsF(ST_X3O, 128, 4, 64, 2048);
  norm_add2<<<(R2*128 + 255)/256, 256, 0, stream>>>(X3O, SA, ST_X3O, X3A, ST_X3A, R2*128);

  // ===== cross-attention props (rows 4096 each) =====
  float* SA1 = SA + (size_t)4096*128;
  auto prop = [&](const float* xbase, float* dst) {
    const float* xin = xbase;
    gemm_qkv<<<dim3(256, 4), 256, 0, stream>>>(xbase, wq, bq, X1B, W_KV, B_KV, X2B, X3A);
    attn_part<<<dim3(2048/64, SPLITK, 8), 256, 0, stream>>>(X1B, X2B, X3A, OP, MLB);
    attn_merge<<<(8*2048*16 + 255)/256, 256, 0, stream>>>(OP, MLB, FANG);
    g32(FANG,128,nullptr,0,0, nullptr,0,nullptr,0,0, nullptr,0,nullptr,0,0, nullptr,nullptr,
        wm, bm, nullptr, X1O, 4096, 128, 128, 0, nullptr, nullptr);
    g32(xin,128,nullptr,0,0, X1O,128,nullptr,0,0, nullptr,0,nullptr,0,0, nullptr,nullptr,
        mw1, mb1, nullptr, ABUF, 4096, 256, 256, 0, nullptr, PARTF);
    statsF(ST_T, 256, 2, 64, 2048);
    g32(ABUF,256,ST_T,1,256, nullptr,0,nullptr,0,0, nullptr,0,nullptr,0,0, nullptr,nullptr,
        mw2, mb2, xin, dst, 4096, 256, 128, 0, nullptr, nullptr);
  };

  prop(SA, XF0);
  prop(SA1, XF1);

  transpose_k<<<dim3(128/32, 2048/32, 4), dim3(32, 8), 0, stream>>>(XF0, (float*)d_out, 2048, 128);
}

// Round 21
// 463.704 us; speedup vs baseline: 2.1007x; 1.0107x over previous
//
#include <hip/hip_runtime.h>
#include <cfloat>
#include <math.h>

#define NPTS 2048
#define R2   8192   // merged: 2 tensors x B=2 x N=2048
#define SPLITK 8

typedef __attribute__((ext_vector_type(8))) short bfrag;
typedef __attribute__((ext_vector_type(4))) float f32x4;

__device__ inline ushort f2bf(float f) {
  unsigned u = __float_as_uint(f);
  return (ushort)((u + 0x7fffu + ((u >> 16) & 1u)) >> 16);
}

// ---------------- fused prologue: prep_weights + transpose2 + knn (independent) ----------------
__global__ __launch_bounds__(256) void prologue(
    const float* __restrict__ conv1, const float* __restrict__ conv2,
    const float* __restrict__ a1w1, const float* __restrict__ a1w2,
    const float* __restrict__ a2w1, const float* __restrict__ a2w2,
    const float* __restrict__ gw2,
    const float* __restrict__ wk, const float* __restrict__ bk,
    const float* __restrict__ wv, const float* __restrict__ bv,
    float* __restrict__ dwA1, float* __restrict__ a1w2r,
    float* __restrict__ dwA2, float* __restrict__ a2w2r,
    float* __restrict__ gw2r, float* __restrict__ dwC1, float* __restrict__ dwC2,
    float* __restrict__ wkv, float* __restrict__ bkv,
    const float* __restrict__ in0, const float* __restrict__ in1, float* __restrict__ FT,
    const float* __restrict__ P0, const float* __restrict__ P1,
    int* __restrict__ idx, float* __restrict__ cosv)
{
  int bid = blockIdx.x, tid = threadIdx.x;
  if (bid < 256) {
    // ---- prep_weights body ----
    int i = bid * 256 + tid;
    if (i < 512*128) {
      int row = i >> 7, c = i & 127;
      float v1, v2;
      if (row < 128) {
        float s1 = 0.f, s2 = 0.f;
        for (int t = 0; t < 3; t++) {
          s1 += a1w1[(row*256 + c)*3 + t] - a1w1[(row*256 + 128 + c)*3 + t];
          s2 += a2w1[(row*256 + c)*3 + t] - a2w1[(row*256 + 128 + c)*3 + t];
        }
        v1 = s1; v2 = s2;
      } else {
        int t = (row - 128) >> 7, o = row & 127;
        v1 = a1w1[(o*256 + 128 + c)*3 + t];
        v2 = a2w1[(o*256 + 128 + c)*3 + t];
      }
      dwA1[i] = v1; dwA2[i] = v2;
      dwC2[i] = (row < 256) ? (conv2[row*256 + c] - conv2[row*256 + 128 + c])
                            : conv2[(row-256)*256 + 128 + c];
    }
    if (i < 128*384) {
      int o = i / 384, rem = i % 384, w = rem >> 7, c = rem & 127;
      a1w2r[i] = a1w2[(o*128 + c)*3 + w];
      a2w2r[i] = a2w2[(o*128 + c)*3 + w];
      gw2r[i]  = gw2[(o*128 + c)*3 + w];
    }
    if (i < 256*128) {
      int row = i >> 7, c = i & 127;
      dwC1[i] = (row < 128) ? (conv1[row*256 + c] - conv1[row*256 + 128 + c])
                            : conv1[(row-128)*256 + 128 + c];
      wkv[i] = (row < 128) ? wk[row*128 + c] : wv[(row-128)*128 + c];
    }
    if (i < 256) bkv[i] = (i < 128) ? bk[i] : bv[i - 128];
    return;
  }
  if (bid < 1280) {
    // ---- transpose2 body (I=128, J=2048) ----
    __shared__ float tile[32][33];
    int q = bid - 256;
    int zb = q >> 8, rem = q & 255, by = rem >> 6, bx = rem & 63;
    const float* src = (zb < 2) ? (in0 + (size_t)zb*128*2048) : (in1 + (size_t)(zb-2)*128*2048);
    float* dst = FT + (size_t)zb*2048*128;
    int i0 = by * 32, j0 = bx * 32;
    int tx = tid & 31, ty = tid >> 5;
    for (int s = 0; s < 32; s += 8)
      tile[ty + s][tx] = src[(size_t)(i0 + ty + s)*2048 + (j0 + tx)];
    __syncthreads();
    for (int s = 0; s < 32; s += 8)
      dst[(size_t)(j0 + ty + s)*128 + (i0 + tx)] = tile[tx][ty + s];
    return;
  }
  // ---- knn v5: tournament with incremental lane argmin (exact lex order) ----
  {
    __shared__ float px[NPTS], py[NPTS], sq[NPTS];
    int gw = (bid - 1280) * 4 + (tid >> 6);
    int b4 = gw >> 11, n = gw & 2047;
    int lane = tid & 63;
    const float* Pb = (b4 < 2) ? (P0 + (size_t)b4 * 2 * NPTS) : (P1 + (size_t)(b4 - 2) * 2 * NPTS);
    for (int i = tid; i < NPTS; i += 256) {
      float x = Pb[i], y = Pb[NPTS + i];
      px[i] = x; py[i] = y;
      sq[i] = __fadd_rn(__fmul_rn(x, x), __fmul_rn(y, y));
    }
    __syncthreads();
    float xn = px[n], yn = py[n], sqn = sq[n];
    float d32[32];
#pragma unroll
    for (int j = 0; j < 32; j++) {
      int m = lane + j*64;
      float dot  = __fadd_rn(__fmul_rn(xn, px[m]), __fmul_rn(yn, py[m]));
      float dist = __fsub_rn(__fadd_rn(sqn, sq[m]), __fmul_rn(2.0f, dot));
      d32[j] = fmaxf(dist, 1e-12f);
    }
    float bv2 = d32[0]; int bj = 0;
#pragma unroll
    for (int j = 1; j < 32; j++) {
      bool lt = d32[j] < bv2;
      bv2 = lt ? d32[j] : bv2;
      bj = lt ? j : bj;
    }
    for (int r = 0; r < 10; r++) {
      float wvv = bv2;
      int   wii = lane + bj*64;
      for (int off = 32; off >= 1; off >>= 1) {
        float od = __shfl_xor(wvv, off);
        int   oi = __shfl_xor(wii, off);
        if (od < wvv || (od == wvv && oi < wii)) { wvv = od; wii = oi; }
      }
      if (r > 0 && lane == 0) {
        size_t base = (size_t)gw*9 + (r - 1);
        idx[base] = wii;
        float dot = __fadd_rn(__fmul_rn(xn, px[wii]), __fmul_rn(yn, py[wii]));
        cosv[base] = __fdiv_rn(dot, __fmul_rn(__fsqrt_rn(sqn), __fsqrt_rn(sq[wii])));
      }
      if ((wii & 63) == lane) {
        int wj = wii >> 6;
#pragma unroll
        for (int j = 0; j < 32; j++) if (j == wj) d32[j] = FLT_MAX;
        bv2 = d32[0]; bj = 0;
#pragma unroll
        for (int j = 1; j < 32; j++) {
          bool lt = d32[j] < bv2;
          bv2 = lt ? d32[j] : bv2;
          bj = lt ? j : bj;
        }
      }
    }
  }
}

// ---------------- transpose [b][I][J] -> [b][J][I] (final output, z=4) ----------------
__global__ void transpose_k(const float* __restrict__ in, float* __restrict__ out, int I, int J) {
  __shared__ float tile[32][33];
  int b = blockIdx.z;
  int i0 = blockIdx.y * 32, j0 = blockIdx.x * 32;
  int tx = threadIdx.x, ty = threadIdx.y;
  for (int s = 0; s < 32; s += 8)
    tile[ty + s][tx] = in[((size_t)b*I + (i0 + ty + s))*J + (j0 + tx)];
  __syncthreads();
  for (int s = 0; s < 32; s += 8)
    out[((size_t)b*J + (j0 + ty + s))*I + (i0 + tx)] = tile[tx][ty + s];
}

// ---------------- bf16-MFMA GEMM device body ----------------
// pack!=0 epilogue writes bf16 (ushort) into Y/Y2 head-packed layouts.
template<int BM>
__device__ __forceinline__ void gemm_body(
    const float* __restrict__ p0, int w0, const float* __restrict__ st0, int a0, int xm0,
    const float* __restrict__ p1, int w1, const float* __restrict__ st1, int a1, int xm1,
    const float* __restrict__ p2, int w2, const float* __restrict__ st2, int a2, int xm2,
    const float* __restrict__ addp, const float* __restrict__ addst,
    const float* __restrict__ W, const float* __restrict__ bias,
    const float* __restrict__ resid,
    float* __restrict__ Y, int Cin, int O, int pack, float* __restrict__ Y2,
    float* __restrict__ part,
    int r0, int c0, int pbx)
{
  __shared__ ushort Xs[BM][40];   // bf16, 80B row stride (16B-aligned frag reads)
  __shared__ ushort Ws[64][40];
  constexpr int RT = BM / 16;
  constexpr int XF = BM / 8;
  int tid = threadIdx.x;
  int wv = tid >> 6, l = tid & 63;
  int m16 = l & 15, kq = l >> 4;
  int sxr = tid & (BM - 1), sxc = (tid / BM) * XF;
  int swr = tid & 63, swc = (tid >> 6) * 8;
  f32x4 acc[RT];
#pragma unroll
  for (int t = 0; t < RT; t++) acc[t] = (f32x4){0.f, 0.f, 0.f, 0.f};
  for (int k0 = 0; k0 < Cin; k0 += 32) {
    {
      int r = r0 + sxr;
      int ac = k0 + sxc;
      const float* P; const float* st; int cc, lw, act, xm;
      if (ac < w0)            { P = p0; cc = ac;          lw = w0; st = st0; act = a0; xm = xm0; }
      else if (ac < w0 + w1)  { P = p1; cc = ac - w0;     lw = w1; st = st1; act = a1; xm = xm1; }
      else                    { P = p2; cc = ac - w0 - w1; lw = w2; st = st2; act = a2; xm = xm2; }
      float vv[XF];
#pragma unroll
      for (int q = 0; q < XF; q += 4)
        *(float4*)&vv[q] = *(const float4*)(P + (size_t)r*lw + cc + q);
      int b = r >> 11;
      if (st) {
#pragma unroll
        for (int j = 0; j < XF; j++) {
          int o = (cc + j) & (xm - 1);
          float m = st[(b*xm + o)*2], rs = st[(b*xm + o)*2 + 1];
          float v = (vv[j] - m) * rs;
          vv[j] = (act == 1) ? fmaxf(v, 0.f) : ((v >= 0.f) ? v : 0.2f*v);
        }
      }
      if (addp && ac >= 128) {
        int fc = (ac - 128) & 127;
        float av[XF];
#pragma unroll
        for (int q = 0; q < XF; q += 4)
          *(float4*)&av[q] = *(const float4*)(addp + (size_t)r*128 + fc + q);
        if (addst) {
#pragma unroll
          for (int j = 0; j < XF; j++) {
            int o = (fc + j) & 127;
            float m = addst[(b*128 + o)*2], rs = addst[(b*128 + o)*2 + 1];
            av[j] = fmaxf((av[j] - m) * rs, 0.f);
          }
        }
#pragma unroll
        for (int j = 0; j < XF; j++) vv[j] += av[j];
      }
      union { ushort u[XF]; ushort4 v4[XF/4]; } pk;
#pragma unroll
      for (int j = 0; j < XF; j++) pk.u[j] = f2bf(vv[j]);
#pragma unroll
      for (int q = 0; q < XF/4; q++) *(ushort4*)&Xs[sxr][sxc + q*4] = pk.v4[q];
    }
    {
      const float* s = W + (size_t)(c0 + swr)*Cin + k0 + swc;
      float4 v0 = *(const float4*)s, v1 = *(const float4*)(s + 4);
      union { ushort u[8]; ushort4 v4[2]; } pk;
      pk.u[0]=f2bf(v0.x); pk.u[1]=f2bf(v0.y); pk.u[2]=f2bf(v0.z); pk.u[3]=f2bf(v0.w);
      pk.u[4]=f2bf(v1.x); pk.u[5]=f2bf(v1.y); pk.u[6]=f2bf(v1.z); pk.u[7]=f2bf(v1.w);
      *(ushort4*)&Ws[swr][swc]     = pk.v4[0];
      *(ushort4*)&Ws[swr][swc + 4] = pk.v4[1];
    }
    __syncthreads();
    bfrag bf = *(const bfrag*)&Ws[wv*16 + m16][kq*8];
#pragma unroll
    for (int t = 0; t < RT; t++) {
      bfrag af = *(const bfrag*)&Xs[t*16 + m16][kq*8];
      acc[t] = __builtin_amdgcn_mfma_f32_16x16x32_bf16(af, bf, acc[t], 0, 0, 0);
    }
    __syncthreads();
  }
  int c = c0 + wv*16 + m16;
  float bi = bias ? bias[c] : 0.f;
  float ps = 0.f, ps2 = 0.f;
#pragma unroll
  for (int t = 0; t < RT; t++) {
#pragma unroll
    for (int i = 0; i < 4; i++) {
      int r = r0 + t*16 + kq*4 + i;
      float v = acc[t][i] + bi;
      if (resid) v += resid[(size_t)r*O + c];
      if (pack) {
        int cc2 = c & 127;
        int h = cc2 & 3, dd = cc2 >> 2, b = r >> 11, n = r & 2047;
        float* T = (pack == 1 || c < 128) ? Y : Y2;
        ((ushort*)T)[(((size_t)(b*4 + h))*NPTS + n)*32 + dd] = f2bf(v);
      } else {
        Y[(size_t)r*O + c] = v;
      }
      ps += v; ps2 = fmaf(v, v, ps2);
    }
  }
  if (part) {
    ps  += __shfl_xor(ps, 16);  ps  += __shfl_xor(ps, 32);
    ps2 += __shfl_xor(ps2, 16); ps2 += __shfl_xor(ps2, 32);
    if (kq == 0) {
      part[((size_t)pbx*O + c)*2]     = ps;
      part[((size_t)pbx*O + c)*2 + 1] = ps2;
    }
  }
}

template<int BM>
__global__ __launch_bounds__(256) void gemm_m(
    const float* __restrict__ p0, int w0, const float* __restrict__ st0, int a0, int xm0,
    const float* __restrict__ p1, int w1, const float* __restrict__ st1, int a1, int xm1,
    const float* __restrict__ p2, int w2, const float* __restrict__ st2, int a2, int xm2,
    const float* __restrict__ addp, const float* __restrict__ addst,
    const float* __restrict__ W, const float* __restrict__ bias,
    const float* __restrict__ resid,
    float* __restrict__ Y, int Cin, int O, int pack, float* __restrict__ Y2,
    float* __restrict__ part)
{
  gemm_body<BM>(p0,w0,st0,a0,xm0, p1,w1,st1,a1,xm1, p2,w2,st2,a2,xm2,
                addp,addst, W,bias,resid, Y,Cin,O,pack,Y2,part,
                blockIdx.x*BM, blockIdx.y*64, blockIdx.x);
}

// fused Q + KV projection: X rows [0..4095]=xin (Q), [4096..8191]=src (KV); bf16 outputs
__global__ __launch_bounds__(256) void gemm_qkv(
    const float* __restrict__ Xbase,
    const float* __restrict__ wq, const float* __restrict__ bq, float* __restrict__ Qo,
    const float* __restrict__ wkv, const float* __restrict__ bkv, float* __restrict__ Ko,
    float* __restrict__ Vo)
{
  int bx = blockIdx.x, by = blockIdx.y;
  if (bx < 128) {
    if (by >= 2) return;
    gemm_body<32>(Xbase,128,nullptr,0,0, nullptr,0,nullptr,0,0, nullptr,0,nullptr,0,0,
                  nullptr,nullptr, wq, bq, nullptr, Qo, 128, 128, 1, nullptr, nullptr,
                  bx*32, by*64, 0);
  } else {
    gemm_body<32>(Xbase + (size_t)4096*128,128,nullptr,0,0, nullptr,0,nullptr,0,0, nullptr,0,nullptr,0,0,
                  nullptr,nullptr, wkv, bkv, nullptr, Ko, 128, 256, 2, Vo, nullptr,
                  (bx-128)*32, by*64, 0);
  }
}

// ---------------- annu conv1 combine: 4 rows/block + fused f64 stats partials ----------------
__global__ __launch_bounds__(256) void combine_annu(const float* __restrict__ GA, const int* __restrict__ idx,
                                                    const float* __restrict__ b1, float* __restrict__ A,
                                                    double* __restrict__ part) {
  int t = threadIdx.x;
  int o = t & 127, sub = t >> 7;
  int r0 = blockIdx.x * 4;
  __shared__ int nbs[4][9];
  if (t < 36) nbs[t / 9][t % 9] = idx[(size_t)(r0 + t/9)*9 + (t % 9)];
  __syncthreads();
  float bo = b1[o];
  double s = 0.0, s2 = 0.0;
  for (int rr = sub; rr < 4; rr += 2) {
    int r = r0 + rr, rb = r & ~2047;
    float ctr = GA[(size_t)r*512 + o] + bo;
#pragma unroll
    for (int w = 0; w < 3; w++) {
      float acc = ctr;
#pragma unroll
      for (int t3 = 0; t3 < 3; t3++) {
        int m = nbs[rr][w*3 + t3];
        acc += GA[(size_t)(rb + m)*512 + 128 + t3*128 + o];
      }
      A[(size_t)r*384 + w*128 + o] = acc;
      s += (double)acc; s2 += (double)acc * (double)acc;
    }
  }
  __shared__ double ls[256], ls2[256];
  ls[t] = s; ls2[t] = s2;
  __syncthreads();
  if (sub == 0) {
    s += ls[128 + o]; s2 += ls2[128 + o];
    part[((size_t)blockIdx.x*128 + o)*2] = s;
    part[((size_t)blockIdx.x*128 + o)*2 + 1] = s2;
  }
}

// ---------------- fused: gm_final_f(ST_X1B) || cos_conv (disjoint partial regions) ----------------
__global__ __launch_bounds__(256) void stats_cos(const float* __restrict__ partf, float* __restrict__ stat,
                                                 const float* __restrict__ cosv, const float* __restrict__ gw1,
                                                 const float* __restrict__ gb1, float* __restrict__ ANG,
                                                 double* __restrict__ part2) {
  int bid = blockIdx.x, t = threadIdx.x;
  if (bid < 64) {
    int g = bid * 8 + (t >> 5);
    int lane = t & 31;
    if (g >= 512) return;
    int b = g >> 7, o = g & 127;
    double S = 0.0, S2 = 0.0;
    for (int u = lane; u < 64; u += 32) {
      size_t blk = (size_t)(b*64 + u);
      S  += (double)partf[(blk*128 + o)*2];
      S2 += (double)partf[(blk*128 + o)*2 + 1];
    }
    for (int off = 16; off >= 1; off >>= 1) {
      S  += __shfl_down(S, off, 32);
      S2 += __shfl_down(S2, off, 32);
    }
    if (lane == 0) {
      double mean = S / 2048;
      double var = S2 / 2048 - mean*mean;
      if (var < 0.0) var = 0.0;
      stat[g*2] = (float)mean;
      stat[g*2 + 1] = (float)(1.0 / sqrt(var + 1e-5));
    }
    return;
  }
  {
    int cbid = bid - 64;
    int o = t & 127, sub = t >> 7;
    int r0 = cbid * 16;
    float g0 = gw1[o*3], g1 = gw1[o*3+1], g2 = gw1[o*3+2], gb = gb1[o];
    __shared__ float cs[16][12];
    for (int i = t; i < 16*9; i += 256) cs[i / 9][i % 9] = cosv[(size_t)(r0 + i/9)*9 + (i % 9)];
    __syncthreads();
    double s = 0.0, s2 = 0.0;
    for (int rr = sub; rr < 16; rr += 2) {
      int r = r0 + rr;
#pragma unroll
      for (int w = 0; w < 3; w++) {
        float acc = gb;
        acc += cs[rr][w*3+0]*g0;
        acc += cs[rr][w*3+1]*g1;
        acc += cs[rr][w*3+2]*g2;
        ANG[(size_t)r*384 + w*128 + o] = acc;
        s += (double)acc; s2 += (double)acc * (double)acc;
      }
    }
    __shared__ double ls[256], ls2[256];
    ls[t] = s; ls2[t] = s2;
    __syncthreads();
    if (sub == 0) {
      s += ls[128 + o]; s2 += ls2[128 + o];
      part2[((size_t)cbid*128 + o)*2] = s;
      part2[((size_t)cbid*128 + o)*2 + 1] = s2;
    }
  }
}

// ---------------- parallel stats final (f64 partials) ----------------
__global__ __launch_bounds__(256) void gm_final(const double* __restrict__ part, float* __restrict__ stats,
                                                int Cc, int NB, int nblk, int count) {
  int g = blockIdx.x * 8 + (threadIdx.x >> 5);
  int lane = threadIdx.x & 31;
  if (g >= NB*Cc) return;
  int b = g / Cc, o = g % Cc;
  double S = 0.0, S2 = 0.0;
  for (int u = lane; u < nblk; u += 32) {
    size_t blk = (size_t)(b*nblk + u);
    S  += part[(blk*Cc + o)*2];
    S2 += part[(blk*Cc + o)*2 + 1];
  }
  for (int off = 16; off >= 1; off >>= 1) {
    S  += __shfl_down(S, off, 32);
    S2 += __shfl_down(S2, off, 32);
  }
  if (lane == 0) {
    double mean = S / count;
    double var = S2 / count - mean*mean;
    if (var < 0.0) var = 0.0;
    stats[g*2] = (float)mean;
    stats[g*2 + 1] = (float)(1.0 / sqrt(var + 1e-5));
  }
}

// ---------------- parallel stats final (f32 partials, f64 accumulate) ----------------
__global__ __launch_bounds__(256) void gm_final_f(const float* __restrict__ part, float* __restrict__ stats,
                                                  int Cc, int NB, int nblk, int count) {
  int g = blockIdx.x * 8 + (threadIdx.x >> 5);
  int lane = threadIdx.x & 31;
  if (g >= NB*Cc) return;
  int b = g / Cc, o = g % Cc;
  double S = 0.0, S2 = 0.0;
  for (int u = lane; u < nblk; u += 32) {
    size_t blk = (size_t)(b*nblk + u);
    S  += (double)part[(blk*Cc + o)*2];
    S2 += (double)part[(blk*Cc + o)*2 + 1];
  }
  for (int off = 16; off >= 1; off >>= 1) {
    S  += __shfl_down(S, off, 32);
    S2 += __shfl_down(S2, off, 32);
  }
  if (lane == 0) {
    double mean = S / count;
    double var = S2 / count - mean*mean;
    if (var < 0.0) var = 0.0;
    stats[g*2] = (float)mean;
    stats[g*2 + 1] = (float)(1.0 / sqrt(var + 1e-5));
  }
}

// ---------------- gather + max over k + f64 partials (4 rows/block, idx in LDS) ----------------
__global__ __launch_bounds__(256) void gather_max_partial(const float* __restrict__ G, const int* __restrict__ idx,
                                                          float* __restrict__ maxbuf, double* __restrict__ part,
                                                          int Cc) {
  int t = threadIdx.x;
  int o = t % Cc, sub = t / Cc, nsub = 256 / Cc;
  int r0 = blockIdx.x * 4;
  __shared__ int nbs[4][9];
  if (t < 36) nbs[t / 9][t % 9] = idx[(size_t)(r0 + t/9)*9 + (t % 9)];
  __syncthreads();
  double s = 0.0, s2 = 0.0;
  for (int rr = sub; rr < 4; rr += nsub) {
    int r = r0 + rr, rb = r & ~2047;
    float g = G[(size_t)r*2*Cc + o];
    float mx = -3.4e38f;
#pragma unroll
    for (int k = 0; k < 9; k++) {
      int m = nbs[rr][k];
      float v = g + G[(size_t)(rb + m)*2*Cc + Cc + o];
      mx = fmaxf(mx, v); s += (double)v; s2 += (double)v*(double)v;
    }
    maxbuf[(size_t)r*Cc + o] = mx;
  }
  if (nsub == 2) {
    __shared__ double ls[256], ls2[256];
    ls[t] = s; ls2[t] = s2;
    __syncthreads();
    if (sub == 0) { s += ls[Cc + o]; s2 += ls2[Cc + o]; }
  }
  if (sub == 0) {
    part[((size_t)blockIdx.x*Cc + o)*2] = s;
    part[((size_t)blockIdx.x*Cc + o)*2 + 1] = s2;
  }
}

// ---------------- final: SA = lrelu(inorm(X3O)) + lrelu(inorm(X3A)) ----------------
__global__ void norm_add2(const float* __restrict__ src, float* __restrict__ dst,
                          const float* __restrict__ stats,
                          const float* __restrict__ addend, const float* __restrict__ astats,
                          int total) {
  int i = blockIdx.x * 256 + threadIdx.x;
  if (i >= total) return;
  int o = i & 127;
  int b = i >> 18;
  float m = stats[(b*128 + o)*2], rs = stats[(b*128 + o)*2 + 1];
  float v = (src[i] - m) * rs;
  v = (v >= 0.f) ? v : 0.2f*v;
  float ma = astats[(b*128 + o)*2], rsa = astats[(b*128 + o)*2 + 1];
  float a = (addend[i] - ma) * rsa;
  a = (a >= 0.f) ? a : 0.2f*a;
  dst[i] = v + a;
}

// ---------------- MFMA flash attention: bf16 Q/K/V inputs, 64 q-rows/block, split-K 8 ----------------
__global__ __launch_bounds__(256) void attn_part(const ushort* __restrict__ Qp, const ushort* __restrict__ Kp,
                                                 const ushort* __restrict__ Vp,
                                                 float* __restrict__ OP, float* __restrict__ ML) {
  __shared__ ushort Ks[64][40];   // K rows [key][dim], bf16
  __shared__ ushort Vt[32][72];   // V transposed [dim][key], bf16
  __shared__ ushort Pb[64][72];   // P rows [q-row][key 0..63], bf16 (front doubles as Q staging)
  int tid = threadIdx.x;
  int wv = tid >> 6, l = tid & 63;
  int d = l & 15, g = l >> 4;
  int kp = blockIdx.y, bh = blockIdx.z;
  int q0 = blockIdx.x * 64;
  const ushort* Qh = Qp + (size_t)bh * NPTS * 32;
  const ushort* Kh = Kp + (size_t)bh * NPTS * 32;
  const ushort* Vh = Vp + (size_t)bh * NPTS * 32;
  {
    int r = tid >> 2, c8 = (tid & 3) * 8;
    const ushort* q = Qh + (size_t)(q0 + r)*32 + c8;
    *(ushort4*)&Pb[r][c8]     = *(const ushort4*)q;
    *(ushort4*)&Pb[r][c8 + 4] = *(const ushort4*)(q + 4);
  }
  __syncthreads();
  bfrag qf = *(const bfrag*)&Pb[wv*16 + d][g*8];
  f32x4 Oc[2];
  Oc[0] = (f32x4){0.f,0.f,0.f,0.f}; Oc[1] = (f32x4){0.f,0.f,0.f,0.f};
  float m_[4] = {-FLT_MAX, -FLT_MAX, -FLT_MAX, -FLT_MAX};
  float l_[4] = {0.f, 0.f, 0.f, 0.f};
  const float sc = 0.17677669529663687f;   // 1/sqrt(32)
  int ks0 = kp * (NPTS / SPLITK);
  for (int k0 = ks0; k0 < ks0 + NPTS/SPLITK; k0 += 64) {
    __syncthreads();
    {
      int r = tid >> 2, c8 = (tid & 3) * 8;
      const ushort* kr = Kh + (size_t)(k0 + r)*32 + c8;
      *(ushort4*)&Ks[r][c8]     = *(const ushort4*)kr;
      *(ushort4*)&Ks[r][c8 + 4] = *(const ushort4*)(kr + 4);
      int vr = tid & 63, vd = (tid >> 6) * 8;
      const ushort* vp = Vh + (size_t)(k0 + vr)*32 + vd;
      ushort4 b0 = *(const ushort4*)vp, b1 = *(const ushort4*)(vp + 4);
      Vt[vd+0][vr] = b0.x; Vt[vd+1][vr] = b0.y;
      Vt[vd+2][vr] = b0.z; Vt[vd+3][vr] = b0.w;
      Vt[vd+4][vr] = b1.x; Vt[vd+5][vr] = b1.y;
      Vt[vd+6][vr] = b1.z; Vt[vd+7][vr] = b1.w;
    }
    __syncthreads();
    f32x4 S[4];
#pragma unroll
    for (int c = 0; c < 4; c++) {
      S[c] = (f32x4){0.f,0.f,0.f,0.f};
      bfrag kf = *(const bfrag*)&Ks[c*16 + d][g*8];
      S[c] = __builtin_amdgcn_mfma_f32_16x16x32_bf16(qf, kf, S[c], 0, 0, 0);
    }
    float cf[4];
#pragma unroll
    for (int i = 0; i < 4; i++) {
      float tm = fmaxf(fmaxf(S[0][i], S[1][i]), fmaxf(S[2][i], S[3][i])) * sc;
      for (int off = 1; off < 16; off <<= 1) tm = fmaxf(tm, __shfl_xor(tm, off));
      float mn = fmaxf(m_[i], tm);
      cf[i] = __expf(m_[i] - mn);
      m_[i] = mn;
    }
    float rs[4] = {0.f, 0.f, 0.f, 0.f};
    ushort pu[4][4];
#pragma unroll
    for (int c = 0; c < 4; c++)
#pragma unroll
      for (int i = 0; i < 4; i++) {
        float p = __expf(fmaf(S[c][i], sc, -m_[i]));
        rs[i] += p;
        pu[c][i] = f2bf(p);
      }
#pragma unroll
    for (int i = 0; i < 4; i++) {
      float r2 = rs[i];
      for (int off = 1; off < 16; off <<= 1) r2 += __shfl_xor(r2, off);
      l_[i] = l_[i]*cf[i] + r2;
      Oc[0][i] *= cf[i]; Oc[1][i] *= cf[i];
    }
#pragma unroll
    for (int c = 0; c < 4; c++)
#pragma unroll
      for (int i = 0; i < 4; i++)
        Pb[wv*16 + g*4 + i][c*16 + d] = pu[c][i];
#pragma unroll
    for (int s5 = 0; s5 < 2; s5++) {
      bfrag pf = *(const bfrag*)&Pb[wv*16 + d][g*8 + 32*s5];
#pragma unroll
      for (int td = 0; td < 2; td++) {
        union { ushort4 v4[2]; bfrag f; } vu;
        vu.v4[0] = *(const ushort4*)&Vt[td*16 + d][g*8 + 32*s5];
        vu.v4[1] = *(const ushort4*)&Vt[td*16 + d][g*8 + 32*s5 + 4];
        Oc[td] = __builtin_amdgcn_mfma_f32_16x16x32_bf16(pf, vu.f, Oc[td], 0, 0, 0);
      }
    }
  }
  size_t pb = (size_t)(kp*8 + bh) * NPTS;
#pragma unroll
  for (int i = 0; i < 4; i++) {
    int n = q0 + wv*16 + g*4 + i;
    OP[(pb + n)*32 + d]      = Oc[0][i];
    OP[(pb + n)*32 + 16 + d] = Oc[1][i];
    if (d == 0) { ML[(pb + n)*2] = m_[i]; ML[(pb + n)*2 + 1] = l_[i]; }
  }
}

// ---------------- merge the eight K-slices ----------------
__global__ void attn_merge(const float* __restrict__ OP, const float* __restrict__ ML,
                           float* __restrict__ out) {
  int i = blockIdx.x * 256 + threadIdx.x;   // 8*2048*16
  if (i >= 8*2048*16) return;
  int dp = (i & 15) * 2;
  int n  = (i >> 4) & 2047;
  int bh = i >> 15;
  float mv[SPLITK], lv[SPLITK];
  float mm = -FLT_MAX;
#pragma unroll
  for (int p = 0; p < SPLITK; p++) {
    size_t pp = ((size_t)(p*8 + bh) * NPTS + n);
    mv[p] = ML[pp*2]; lv[p] = ML[pp*2 + 1];
    mm = fmaxf(mm, mv[p]);
  }
  float L = 0.f, ox = 0.f, oy = 0.f;
#pragma unroll
  for (int p = 0; p < SPLITK; p++) {
    size_t pp = ((size_t)(p*8 + bh) * NPTS + n);
    float w = __expf(mv[p] - mm);
    L += w * lv[p];
    float2 o = *(const float2*)&OP[pp*32 + dp];
    ox += w * o.x; oy += w * o.y;
  }
  float inv = 1.f / L;
  int b = bh >> 2, h = bh & 3;
  out[((size_t)(b*NPTS + n))*128 + (dp+0)*4 + h] = ox * inv;
  out[((size_t)(b*NPTS + n))*128 + (dp+1)*4 + h] = oy * inv;
}

// ================= host =================
extern "C" void kernel_launch(void* const* d_in, const int* in_sizes, int n_in,
                              void* d_out, int out_size, void* d_ws, size_t ws_size,
                              hipStream_t stream) {
  (void)in_sizes; (void)n_in; (void)out_size; (void)ws_size;
  const float* desc0  = (const float*)d_in[0];
  const float* desc1  = (const float*)d_in[1];
  const float* coords0= (const float*)d_in[2];
  const float* coords1= (const float*)d_in[3];
  const float* conv1w = (const float*)d_in[4];
  const float* conv2w = (const float*)d_in[5];
  const float* conv3w = (const float*)d_in[6];
  const float* conv3ow= (const float*)d_in[7];
  const float* a1w1 = (const float*)d_in[8];
  const float* a1b1 = (const float*)d_in[9];
  const float* a1w2 = (const float*)d_in[10];
  const float* a1b2 = (const float*)d_in[11];
  const float* a2w1 = (const float*)d_in[12];
  const float* a2b1 = (const float*)d_in[13];
  const float* a2w2 = (const float*)d_in[14];
  const float* a2b2 = (const float*)d_in[15];
  const float* gw1  = (const float*)d_in[16];
  const float* gb1  = (const float*)d_in[17];
  const float* gw2  = (const float*)d_in[18];
  const float* gb2  = (const float*)d_in[19];
  const float* wq = (const float*)d_in[20]; const float* bq = (const float*)d_in[21];
  const float* wk = (const float*)d_in[22]; const float* bk = (const float*)d_in[23];
  const float* wv = (const float*)d_in[24]; const float* bv = (const float*)d_in[25];
  const float* wm = (const float*)d_in[26]; const float* bm = (const float*)d_in[27];
  const float* mw1 = (const float*)d_in[28]; const float* mb1 = (const float*)d_in[29];
  const float* mw2 = (const float*)d_in[30]; const float* mb2 = (const float*)d_in[31];

  float* ws = (float*)d_ws;
  size_t off = 0;
  auto alloc = [&](size_t nel) { size_t r = off; off += (nel + 63) & ~(size_t)63; return r; };
  float* DW_A1 = ws + alloc(512*128);
  float* W_A1R = ws + alloc(128*384);
  float* DW_A2 = ws + alloc(512*128);
  float* W_A2R = ws + alloc(128*384);
  float* W_G2R = ws + alloc(128*384);
  float* DW_C1 = ws + alloc(256*128);
  float* DW_C2 = ws + alloc(512*128);
  float* W_KV  = ws + alloc(256*128);
  float* B_KV  = ws + alloc(256);
  float* SA   = ws + alloc((size_t)R2*128);   // SA0 rows 0..4095 | SA1 rows 4096..8191
  float* XF0  = ws + alloc((size_t)4096*128); // contiguous with XF1 for fused z=4 transpose
  float* XF1  = ws + alloc((size_t)4096*128);
  int*   IDX  = (int*)(ws + alloc((size_t)R2*9));
  float* COSV = ws + alloc((size_t)R2*9);
  float* FT   = ws + alloc((size_t)R2*128);
  float* BIG  = ws + alloc((size_t)R2*512);
  float* ABUF = ws + alloc((size_t)R2*384);
  float* X1B  = ws + alloc((size_t)R2*128);
  float* FANG = ws + alloc((size_t)R2*128);
  float* X2B  = ws + alloc((size_t)R2*128);
  float* X3A  = ws + alloc((size_t)R2*128);
  float* X1O  = ws + alloc((size_t)R2*128);
  float* AB2  = ws + alloc((size_t)R2*256);
  float* X3O  = ws + alloc((size_t)R2*128);
  double* PART = (double*)(ws + alloc((size_t)2048*256*2*2));   // 1M doubles (8 MB)
  float*  PARTF = (float*)PART;                                  // aliased f32 partials
  double* PART2 = PART + (size_t)512*1024;                       // disjoint region for cos stats
  float* STATS = ws + alloc(8*2048);
  float* MLB  = ws + alloc((size_t)SPLITK*8*NPTS*2);            // attn m/l partials
  float* ST_T   = STATS;
  float* ST_X1B = STATS + 2048;
  float* ST_FANG= STATS + 4096;
  float* ST_X2B = STATS + 6144;
  float* ST_X3A = STATS + 8192;
  float* ST_X1O = STATS + 10240;
  float* ST_AB  = STATS + 12288;
  float* ST_X3O = STATS + 14336;
  float* OP  = BIG;    // attn O partials: SPLITK*8*2048*32 = R2*512 floats exactly

  auto g64 = [&](const float* p0,int w0,const float* st0,int a0,int x0,
                 const float* p1,int w1,const float* st1,int a1,int x1,
                 const float* p2,int w2,const float* st2,int a2,int x2,
                 const float* addp,const float* addst,
                 const float* W,const float* bias,const float* resid,
                 float* Y,int R,int Cin,int O,int pack,float* Y2,float* part) {
    gemm_m<64><<<dim3(R/64, O/64), 256, 0, stream>>>(p0,w0,st0,a0,x0, p1,w1,st1,a1,x1,
        p2,w2,st2,a2,x2, addp,addst, W,bias,resid, Y,Cin,O,pack,Y2,part);
  };
  auto g32 = [&](const float* p0,int w0,const float* st0,int a0,int x0,
                 const float* p1,int w1,const float* st1,int a1,int x1,
                 const float* p2,int w2,const float* st2,int a2,int x2,
                 const float* addp,const float* addst,
                 const float* W,const float* bias,const float* resid,
                 float* Y,int R,int Cin,int O,int pack,float* Y2,float* part) {
    gemm_m<32><<<dim3(R/32, O/64), 256, 0, stream>>>(p0,w0,st0,a0,x0, p1,w1,st1,a1,x1,
        p2,w2,st2,a2,x2, addp,addst, W,bias,resid, Y,Cin,O,pack,Y2,part);
  };
  auto statsF = [&](float* stat, int O, int NB, int nblk, int count) {
    gm_final_f<<<(NB*O + 7)/8, 256, 0, stream>>>(PARTF, stat, O, NB, nblk, count);
  };
  auto statsD = [&](float* stat, int O, int NB, int nblk, int count) {
    gm_final<<<(NB*O + 7)/8, 256, 0, stream>>>(PART, stat, O, NB, nblk, count);
  };
  auto gathermax = [&](const float* G, float* mx, int Cc, float* stat) {
    gather_max_partial<<<R2/4, 256, 0, stream>>>(G, IDX, mx, PART, Cc);
    statsD(stat, Cc, 4, 512, 2048*9);
  };

  // ===== fused prologue: prep_weights + transpose2 + knn =====
  prologue<<<3328, 256, 0, stream>>>(conv1w, conv2w, a1w1, a1w2, a2w1, a2w2, gw2,
                                     wk, bk, wv, bv,
                                     DW_A1, W_A1R, DW_A2, W_A2R, W_G2R, DW_C1, DW_C2,
                                     W_KV, B_KV,
                                     desc0, desc1, FT,
                                     coords0, coords1, IDX, COSV);

  // ===== merged branch section (both descs, R2 = 8192 rows, 4 instances) =====
  // annu1
  g64(FT,128,nullptr,0,0, nullptr,0,nullptr,0,0, nullptr,0,nullptr,0,0, nullptr,nullptr,
      DW_A1, nullptr, nullptr, BIG, R2, 128, 512, 0, nullptr, nullptr);
  combine_annu<<<R2/4, 256, 0, stream>>>(BIG, IDX, a1b1, ABUF, PART);
  statsD(ST_T, 128, 4, 512, 2048*3);
  g32(ABUF,384,ST_T,1,128, nullptr,0,nullptr,0,0, nullptr,0,nullptr,0,0, nullptr,nullptr,
      W_A1R, a1b2, nullptr, X1B, R2, 384, 128, 0, nullptr, PARTF);
  // fused: statsF(ST_X1B) || cos_conv (f_ang conv1; writes PART2)
  stats_cos<<<64 + R2/16, 256, 0, stream>>>(PARTF, ST_X1B, COSV, gw1, gb1, ABUF, PART2);
  gm_final<<<(4*128 + 7)/8, 256, 0, stream>>>(PART2, ST_T, 128, 4, 128, 2048*3);
  g32(ABUF,384,ST_T,1,128, nullptr,0,nullptr,0,0, nullptr,0,nullptr,0,0, nullptr,nullptr,
      W_G2R, gb2, nullptr, FANG, R2, 384, 128, 0, nullptr, PARTF);
  statsF(ST_FANG, 128, 4, 64, 2048);
  // annu2 (X1B raw, normed in staging)
  g64(X1B,128,ST_X1B,1,128, nullptr,0,nullptr,0,0, nullptr,0,nullptr,0,0, nullptr,nullptr,
      DW_A2, nullptr, nullptr, BIG, R2, 128, 512, 0, nullptr, nullptr);
  combine_annu<<<R2/4, 256, 0, stream>>>(BIG, IDX, a2b1, ABUF, PART);
  statsD(ST_T, 128, 4, 512, 2048*3);
  g32(ABUF,384,ST_T,1,128, nullptr,0,nullptr,0,0, nullptr,0,nullptr,0,0, nullptr,nullptr,
      W_A2R, a2b2, nullptr, X2B, R2, 384, 128, 0, nullptr, PARTF);
  statsF(ST_X2B, 128, 4, 64, 2048);
  // x3 = conv3 @ [x0 | n(x1)+n(fang) | n(x2)+n(fang)]
  g32(FT,128,nullptr,0,0, X1B,128,ST_X1B,1,128, X2B,128,ST_X2B,1,128, FANG,ST_FANG,
      conv3w, nullptr, nullptr, X3A, R2, 384, 128, 0, nullptr, PARTF);
  statsF(ST_X3A, 128, 4, 64, 2048);
  // x1o
  g64(FT,128,nullptr,0,0, nullptr,0,nullptr,0,0, nullptr,0,nullptr,0,0, nullptr,nullptr,
      DW_C1, nullptr, nullptr, BIG, R2, 128, 256, 0, nullptr, nullptr);
  gathermax(BIG, X1O, 128, ST_X1O);
  // x2o (X1O = raw max, normed lrelu in staging)
  g64(X1O,128,ST_X1O,2,128, nullptr,0,nullptr,0,0, nullptr,0,nullptr,0,0, nullptr,nullptr,
      DW_C2, nullptr, nullptr, BIG, R2, 128, 512, 0, nullptr, nullptr);
  gathermax(BIG, AB2, 256, ST_AB);
  // x3o = conv3o @ [x0 | n(x1o) | n(x2o)]
  g32(FT,128,nullptr,0,0, X1O,128,ST_X1O,2,128, AB2,256,ST_AB,2,256, nullptr,nullptr,
      conv3ow, nullptr, nullptr, X3O, R2, 512, 128, 0, nullptr, PARTF);
  statsF(ST_X3O, 128, 4, 64, 2048);
  norm_add2<<<(R2*128 + 255)/256, 256, 0, stream>>>(X3O, SA, ST_X3O, X3A, ST_X3A, R2*128);

  // ===== cross-attention props (rows 4096 each) =====
  float* SA1 = SA + (size_t)4096*128;
  auto prop = [&](const float* xbase, float* dst) {
    const float* xin = xbase;
    gemm_qkv<<<dim3(256, 4), 256, 0, stream>>>(xbase, wq, bq, X1B, W_KV, B_KV, X2B, X3A);
    attn_part<<<dim3(2048/64, SPLITK, 8), 256, 0, stream>>>(
        (const ushort*)X1B, (const ushort*)X2B, (const ushort*)X3A, OP, MLB);
    attn_merge<<<(8*2048*16 + 255)/256, 256, 0, stream>>>(OP, MLB, FANG);
    g32(FANG,128,nullptr,0,0, nullptr,0,nullptr,0,0, nullptr,0,nullptr,0,0, nullptr,nullptr,
        wm, bm, nullptr, X1O, 4096, 128, 128, 0, nullptr, nullptr);
    g32(xin,128,nullptr,0,0, X1O,128,nullptr,0,0, nullptr,0,nullptr,0,0, nullptr,nullptr,
        mw1, mb1, nullptr, ABUF, 4096, 256, 256, 0, nullptr, PARTF);
    statsF(ST_T, 256, 2, 64, 2048);
    g32(ABUF,256,ST_T,1,256, nullptr,0,nullptr,0,0, nullptr,0,nullptr,0,0, nullptr,nullptr,
        mw2, mb2, xin, dst, 4096, 256, 128, 0, nullptr, nullptr);
  };

  prop(SA, XF0);
  prop(SA1, XF1);

  transpose_k<<<dim3(128/32, 2048/32, 4), dim3(32, 8), 0, stream>>>(XF0, (float*)d_out, 2048, 128);
}

// Round 22
// 433.577 us; speedup vs baseline: 2.2467x; 1.0695x over previous
//
#include <hip/hip_runtime.h>
#include <cfloat>
#include <math.h>

#define NPTS 2048
#define R2   8192   // merged: 2 tensors x B=2 x N=2048
#define SPLITK 8

typedef __attribute__((ext_vector_type(8))) short bfrag;
typedef __attribute__((ext_vector_type(4))) float f32x4;

__device__ inline ushort f2bf(float f) {
  unsigned u = __float_as_uint(f);
  return (ushort)((u + 0x7fffu + ((u >> 16) & 1u)) >> 16);
}

// ---------------- fused prologue: prep_weights(+bf16) + transpose2(bf16) + knn ----------------
__global__ __launch_bounds__(256) void prologue(
    const float* __restrict__ conv1, const float* __restrict__ conv2,
    const float* __restrict__ conv3, const float* __restrict__ conv3o,
    const float* __restrict__ a1w1, const float* __restrict__ a1w2,
    const float* __restrict__ a2w1, const float* __restrict__ a2w2,
    const float* __restrict__ gw2,
    const float* __restrict__ wk, const float* __restrict__ bk,
    const float* __restrict__ wv, const float* __restrict__ bv,
    const float* __restrict__ wqi, const float* __restrict__ wmi,
    const float* __restrict__ mw1i, const float* __restrict__ mw2i,
    ushort* __restrict__ dwA1, ushort* __restrict__ a1w2r,
    ushort* __restrict__ dwA2, ushort* __restrict__ a2w2r,
    ushort* __restrict__ gw2r, ushort* __restrict__ dwC1, ushort* __restrict__ dwC2,
    ushort* __restrict__ wkv, float* __restrict__ bkv,
    ushort* __restrict__ wbc3, ushort* __restrict__ wbc3o,
    ushort* __restrict__ wbq, ushort* __restrict__ wbm,
    ushort* __restrict__ wbm1, ushort* __restrict__ wbm2,
    const float* __restrict__ in0, const float* __restrict__ in1, ushort* __restrict__ FT,
    const float* __restrict__ P0, const float* __restrict__ P1,
    int* __restrict__ idx, float* __restrict__ cosv)
{
  int bid = blockIdx.x, tid = threadIdx.x;
  if (bid < 256) {
    // ---- prep_weights body (all outputs bf16 at rest) ----
    int i = bid * 256 + tid;
    if (i < 512*128) {
      int row = i >> 7, c = i & 127;
      float v1, v2;
      if (row < 128) {
        float s1 = 0.f, s2 = 0.f;
        for (int t = 0; t < 3; t++) {
          s1 += a1w1[(row*256 + c)*3 + t] - a1w1[(row*256 + 128 + c)*3 + t];
          s2 += a2w1[(row*256 + c)*3 + t] - a2w1[(row*256 + 128 + c)*3 + t];
        }
        v1 = s1; v2 = s2;
      } else {
        int t = (row - 128) >> 7, o = row & 127;
        v1 = a1w1[(o*256 + 128 + c)*3 + t];
        v2 = a2w1[(o*256 + 128 + c)*3 + t];
      }
      dwA1[i] = f2bf(v1); dwA2[i] = f2bf(v2);
      dwC2[i] = f2bf((row < 256) ? (conv2[row*256 + c] - conv2[row*256 + 128 + c])
                                 : conv2[(row-256)*256 + 128 + c]);
    }
    if (i < 128*384) {
      int o = i / 384, rem = i % 384, w = rem >> 7, c = rem & 127;
      a1w2r[i] = f2bf(a1w2[(o*128 + c)*3 + w]);
      a2w2r[i] = f2bf(a2w2[(o*128 + c)*3 + w]);
      gw2r[i]  = f2bf(gw2[(o*128 + c)*3 + w]);
    }
    if (i < 256*128) {
      int row = i >> 7, c = i & 127;
      dwC1[i] = f2bf((row < 128) ? (conv1[row*256 + c] - conv1[row*256 + 128 + c])
                                 : conv1[(row-128)*256 + 128 + c]);
      wkv[i] = f2bf((row < 128) ? wk[row*128 + c] : wv[(row-128)*128 + c]);
    }
    if (i < 256) bkv[i] = (i < 128) ? bk[i] : bv[i - 128];
    // straight bf16 copies of external weights
    if (i < 128*384) wbc3[i]  = f2bf(conv3[i]);
    if (i < 128*512) wbc3o[i] = f2bf(conv3o[i]);
    if (i < 128*128) { wbq[i] = f2bf(wqi[i]); wbm[i] = f2bf(wmi[i]); }
    if (i < 256*256) wbm1[i] = f2bf(mw1i[i]);
    if (i < 128*256) wbm2[i] = f2bf(mw2i[i]);
    return;
  }
  if (bid < 1280) {
    // ---- transpose2 body (I=128, J=2048), bf16 output ----
    __shared__ float tile[32][33];
    int q = bid - 256;
    int zb = q >> 8, rem = q & 255, by = rem >> 6, bx = rem & 63;
    const float* src = (zb < 2) ? (in0 + (size_t)zb*128*2048) : (in1 + (size_t)(zb-2)*128*2048);
    ushort* dst = FT + (size_t)zb*2048*128;
    int i0 = by * 32, j0 = bx * 32;
    int tx = tid & 31, ty = tid >> 5;
    for (int s = 0; s < 32; s += 8)
      tile[ty + s][tx] = src[(size_t)(i0 + ty + s)*2048 + (j0 + tx)];
    __syncthreads();
    for (int s = 0; s < 32; s += 8)
      dst[(size_t)(j0 + ty + s)*128 + (i0 + tx)] = f2bf(tile[tx][ty + s]);
    return;
  }
  // ---- knn v5: tournament with incremental lane argmin (exact lex order) ----
  {
    __shared__ float px[NPTS], py[NPTS], sq[NPTS];
    int gw = (bid - 1280) * 4 + (tid >> 6);
    int b4 = gw >> 11, n = gw & 2047;
    int lane = tid & 63;
    const float* Pb = (b4 < 2) ? (P0 + (size_t)b4 * 2 * NPTS) : (P1 + (size_t)(b4 - 2) * 2 * NPTS);
    for (int i = tid; i < NPTS; i += 256) {
      float x = Pb[i], y = Pb[NPTS + i];
      px[i] = x; py[i] = y;
      sq[i] = __fadd_rn(__fmul_rn(x, x), __fmul_rn(y, y));
    }
    __syncthreads();
    float xn = px[n], yn = py[n], sqn = sq[n];
    float d32[32];
#pragma unroll
    for (int j = 0; j < 32; j++) {
      int m = lane + j*64;
      float dot  = __fadd_rn(__fmul_rn(xn, px[m]), __fmul_rn(yn, py[m]));
      float dist = __fsub_rn(__fadd_rn(sqn, sq[m]), __fmul_rn(2.0f, dot));
      d32[j] = fmaxf(dist, 1e-12f);
    }
    float bv2 = d32[0]; int bj = 0;
#pragma unroll
    for (int j = 1; j < 32; j++) {
      bool lt = d32[j] < bv2;
      bv2 = lt ? d32[j] : bv2;
      bj = lt ? j : bj;
    }
    for (int r = 0; r < 10; r++) {
      float wvv = bv2;
      int   wii = lane + bj*64;
      for (int off = 32; off >= 1; off >>= 1) {
        float od = __shfl_xor(wvv, off);
        int   oi = __shfl_xor(wii, off);
        if (od < wvv || (od == wvv && oi < wii)) { wvv = od; wii = oi; }
      }
      if (r > 0 && lane == 0) {
        size_t base = (size_t)gw*9 + (r - 1);
        idx[base] = wii;
        float dot = __fadd_rn(__fmul_rn(xn, px[wii]), __fmul_rn(yn, py[wii]));
        cosv[base] = __fdiv_rn(dot, __fmul_rn(__fsqrt_rn(sqn), __fsqrt_rn(sq[wii])));
      }
      if ((wii & 63) == lane) {
        int wj = wii >> 6;
#pragma unroll
        for (int j = 0; j < 32; j++) if (j == wj) d32[j] = FLT_MAX;
        bv2 = d32[0]; bj = 0;
#pragma unroll
        for (int j = 1; j < 32; j++) {
          bool lt = d32[j] < bv2;
          bv2 = lt ? d32[j] : bv2;
          bj = lt ? j : bj;
        }
      }
    }
  }
}

// ---------------- transpose [b][I][J] -> [b][J][I] (final output, z=4) ----------------
__global__ void transpose_k(const float* __restrict__ in, float* __restrict__ out, int I, int J) {
  __shared__ float tile[32][33];
  int b = blockIdx.z;
  int i0 = blockIdx.y * 32, j0 = blockIdx.x * 32;
  int tx = threadIdx.x, ty = threadIdx.y;
  for (int s = 0; s < 32; s += 8)
    tile[ty + s][tx] = in[((size_t)b*I + (i0 + ty + s))*J + (j0 + tx)];
  __syncthreads();
  for (int s = 0; s < 32; s += 8)
    out[((size_t)b*J + (j0 + ty + s))*I + (i0 + tx)] = tile[tx][ty + s];
}

// ---------------- bf16-MFMA GEMM device body (bf16-at-rest W; optional bf16 p0) ----------------
template<int BM>
__device__ __forceinline__ void gemm_body(
    const float* __restrict__ p0, int w0, const float* __restrict__ st0, int a0, int xm0, int xbf0,
    const float* __restrict__ p1, int w1, const float* __restrict__ st1, int a1, int xm1,
    const float* __restrict__ p2, int w2, const float* __restrict__ st2, int a2, int xm2,
    const float* __restrict__ addp, const float* __restrict__ addst,
    const ushort* __restrict__ W, const float* __restrict__ bias,
    const float* __restrict__ resid,
    float* __restrict__ Y, int Cin, int O, int pack, float* __restrict__ Y2,
    float* __restrict__ part,
    int r0, int c0, int pbx)
{
  __shared__ ushort Xs[BM][40];   // bf16, 80B row stride (16B-aligned frag reads)
  __shared__ ushort Ws[64][40];
  constexpr int RT = BM / 16;
  constexpr int XF = BM / 8;
  int tid = threadIdx.x;
  int wv = tid >> 6, l = tid & 63;
  int m16 = l & 15, kq = l >> 4;
  int sxr = tid & (BM - 1), sxc = (tid / BM) * XF;
  int swr = tid & 63, swc = (tid >> 6) * 8;
  f32x4 acc[RT];
#pragma unroll
  for (int t = 0; t < RT; t++) acc[t] = (f32x4){0.f, 0.f, 0.f, 0.f};
  for (int k0 = 0; k0 < Cin; k0 += 32) {
    {
      int r = r0 + sxr;
      int ac = k0 + sxc;
      if (xbf0 && ac < w0) {
        // p0 is bf16 at rest (raw, no stats): pure ushort copies
        const ushort* Pb = (const ushort*)p0 + (size_t)r*w0 + ac;
        *(ushort4*)&Xs[sxr][sxc] = *(const ushort4*)Pb;
        if (XF == 8) *(ushort4*)&Xs[sxr][sxc + 4] = *(const ushort4*)(Pb + 4);
      } else {
        const float* P; const float* st; int cc, lw, act, xm;
        if (ac < w0)            { P = p0; cc = ac;          lw = w0; st = st0; act = a0; xm = xm0; }
        else if (ac < w0 + w1)  { P = p1; cc = ac - w0;     lw = w1; st = st1; act = a1; xm = xm1; }
        else                    { P = p2; cc = ac - w0 - w1; lw = w2; st = st2; act = a2; xm = xm2; }
        float vv[XF];
#pragma unroll
        for (int q = 0; q < XF; q += 4)
          *(float4*)&vv[q] = *(const float4*)(P + (size_t)r*lw + cc + q);
        int b = r >> 11;
        if (st) {
#pragma unroll
          for (int j = 0; j < XF; j++) {
            int o = (cc + j) & (xm - 1);
            float m = st[(b*xm + o)*2], rs = st[(b*xm + o)*2 + 1];
            float v = (vv[j] - m) * rs;
            vv[j] = (act == 1) ? fmaxf(v, 0.f) : ((v >= 0.f) ? v : 0.2f*v);
          }
        }
        if (addp && ac >= 128) {
          int fc = (ac - 128) & 127;
          float av[XF];
#pragma unroll
          for (int q = 0; q < XF; q += 4)
            *(float4*)&av[q] = *(const float4*)(addp + (size_t)r*128 + fc + q);
          if (addst) {
#pragma unroll
            for (int j = 0; j < XF; j++) {
              int o = (fc + j) & 127;
              float m = addst[(b*128 + o)*2], rs = addst[(b*128 + o)*2 + 1];
              av[j] = fmaxf((av[j] - m) * rs, 0.f);
            }
          }
#pragma unroll
          for (int j = 0; j < XF; j++) vv[j] += av[j];
        }
        union { ushort u[XF]; ushort4 v4[XF/4]; } pk;
#pragma unroll
        for (int j = 0; j < XF; j++) pk.u[j] = f2bf(vv[j]);
#pragma unroll
        for (int q = 0; q < XF/4; q++) *(ushort4*)&Xs[sxr][sxc + q*4] = pk.v4[q];
      }
    }
    {
      // W already bf16 at rest: pure ushort copies
      const ushort* s = W + (size_t)(c0 + swr)*Cin + k0 + swc;
      *(ushort4*)&Ws[swr][swc]     = *(const ushort4*)s;
      *(ushort4*)&Ws[swr][swc + 4] = *(const ushort4*)(s + 4);
    }
    __syncthreads();
    bfrag bf = *(const bfrag*)&Ws[wv*16 + m16][kq*8];
#pragma unroll
    for (int t = 0; t < RT; t++) {
      bfrag af = *(const bfrag*)&Xs[t*16 + m16][kq*8];
      acc[t] = __builtin_amdgcn_mfma_f32_16x16x32_bf16(af, bf, acc[t], 0, 0, 0);
    }
    __syncthreads();
  }
  int c = c0 + wv*16 + m16;
  float bi = bias ? bias[c] : 0.f;
  float ps = 0.f, ps2 = 0.f;
#pragma unroll
  for (int t = 0; t < RT; t++) {
#pragma unroll
    for (int i = 0; i < 4; i++) {
      int r = r0 + t*16 + kq*4 + i;
      float v = acc[t][i] + bi;
      if (resid) v += resid[(size_t)r*O + c];
      if (pack) {
        int cc2 = c & 127;
        int h = cc2 & 3, dd = cc2 >> 2, b = r >> 11, n = r & 2047;
        float* T = (pack == 1 || c < 128) ? Y : Y2;
        ((ushort*)T)[(((size_t)(b*4 + h))*NPTS + n)*32 + dd] = f2bf(v);
      } else {
        Y[(size_t)r*O + c] = v;
      }
      ps += v; ps2 = fmaf(v, v, ps2);
    }
  }
  if (part) {
    ps  += __shfl_xor(ps, 16);  ps  += __shfl_xor(ps, 32);
    ps2 += __shfl_xor(ps2, 16); ps2 += __shfl_xor(ps2, 32);
    if (kq == 0) {
      part[((size_t)pbx*O + c)*2]     = ps;
      part[((size_t)pbx*O + c)*2 + 1] = ps2;
    }
  }
}

template<int BM>
__global__ __launch_bounds__(256) void gemm_m(
    const float* __restrict__ p0, int w0, const float* __restrict__ st0, int a0, int xm0, int xbf0,
    const float* __restrict__ p1, int w1, const float* __restrict__ st1, int a1, int xm1,
    const float* __restrict__ p2, int w2, const float* __restrict__ st2, int a2, int xm2,
    const float* __restrict__ addp, const float* __restrict__ addst,
    const ushort* __restrict__ W, const float* __restrict__ bias,
    const float* __restrict__ resid,
    float* __restrict__ Y, int Cin, int O, int pack, float* __restrict__ Y2,
    float* __restrict__ part)
{
  gemm_body<BM>(p0,w0,st0,a0,xm0,xbf0, p1,w1,st1,a1,xm1, p2,w2,st2,a2,xm2,
                addp,addst, W,bias,resid, Y,Cin,O,pack,Y2,part,
                blockIdx.x*BM, blockIdx.y*64, blockIdx.x);
}

// fused Q + KV projection: X rows [0..4095]=xin (Q), [4096..8191]=src (KV); bf16 outputs
__global__ __launch_bounds__(256) void gemm_qkv(
    const float* __restrict__ Xbase,
    const ushort* __restrict__ wq, const float* __restrict__ bq, float* __restrict__ Qo,
    const ushort* __restrict__ wkv, const float* __restrict__ bkv, float* __restrict__ Ko,
    float* __restrict__ Vo)
{
  int bx = blockIdx.x, by = blockIdx.y;
  if (bx < 128) {
    if (by >= 2) return;
    gemm_body<32>(Xbase,128,nullptr,0,0,0, nullptr,0,nullptr,0,0, nullptr,0,nullptr,0,0,
                  nullptr,nullptr, wq, bq, nullptr, Qo, 128, 128, 1, nullptr, nullptr,
                  bx*32, by*64, 0);
  } else {
    gemm_body<32>(Xbase + (size_t)4096*128,128,nullptr,0,0,0, nullptr,0,nullptr,0,0, nullptr,0,nullptr,0,0,
                  nullptr,nullptr, wkv, bkv, nullptr, Ko, 128, 256, 2, Vo, nullptr,
                  (bx-128)*32, by*64, 0);
  }
}

// ---------------- annu conv1 combine: 4 rows/block + fused f64 stats partials ----------------
__global__ __launch_bounds__(256) void combine_annu(const float* __restrict__ GA, const int* __restrict__ idx,
                                                    const float* __restrict__ b1, float* __restrict__ A,
                                                    double* __restrict__ part) {
  int t = threadIdx.x;
  int o = t & 127, sub = t >> 7;
  int r0 = blockIdx.x * 4;
  __shared__ int nbs[4][9];
  if (t < 36) nbs[t / 9][t % 9] = idx[(size_t)(r0 + t/9)*9 + (t % 9)];
  __syncthreads();
  float bo = b1[o];
  double s = 0.0, s2 = 0.0;
  for (int rr = sub; rr < 4; rr += 2) {
    int r = r0 + rr, rb = r & ~2047;
    float ctr = GA[(size_t)r*512 + o] + bo;
#pragma unroll
    for (int w = 0; w < 3; w++) {
      float acc = ctr;
#pragma unroll
      for (int t3 = 0; t3 < 3; t3++) {
        int m = nbs[rr][w*3 + t3];
        acc += GA[(size_t)(rb + m)*512 + 128 + t3*128 + o];
      }
      A[(size_t)r*384 + w*128 + o] = acc;
      s += (double)acc; s2 += (double)acc * (double)acc;
    }
  }
  __shared__ double ls[256], ls2[256];
  ls[t] = s; ls2[t] = s2;
  __syncthreads();
  if (sub == 0) {
    s += ls[128 + o]; s2 += ls2[128 + o];
    part[((size_t)blockIdx.x*128 + o)*2] = s;
    part[((size_t)blockIdx.x*128 + o)*2 + 1] = s2;
  }
}

// ---------------- fused: gm_final_f(ST_X1B) || cos_conv (disjoint partial regions) ----------------
__global__ __launch_bounds__(256) void stats_cos(const float* __restrict__ partf, float* __restrict__ stat,
                                                 const float* __restrict__ cosv, const float* __restrict__ gw1,
                                                 const float* __restrict__ gb1, float* __restrict__ ANG,
                                                 double* __restrict__ part2) {
  int bid = blockIdx.x, t = threadIdx.x;
  if (bid < 64) {
    int g = bid * 8 + (t >> 5);
    int lane = t & 31;
    if (g >= 512) return;
    int b = g >> 7, o = g & 127;
    double S = 0.0, S2 = 0.0;
    for (int u = lane; u < 64; u += 32) {
      size_t blk = (size_t)(b*64 + u);
      S  += (double)partf[(blk*128 + o)*2];
      S2 += (double)partf[(blk*128 + o)*2 + 1];
    }
    for (int off = 16; off >= 1; off >>= 1) {
      S  += __shfl_down(S, off, 32);
      S2 += __shfl_down(S2, off, 32);
    }
    if (lane == 0) {
      double mean = S / 2048;
      double var = S2 / 2048 - mean*mean;
      if (var < 0.0) var = 0.0;
      stat[g*2] = (float)mean;
      stat[g*2 + 1] = (float)(1.0 / sqrt(var + 1e-5));
    }
    return;
  }
  {
    int cbid = bid - 64;
    int o = t & 127, sub = t >> 7;
    int r0 = cbid * 16;
    float g0 = gw1[o*3], g1 = gw1[o*3+1], g2 = gw1[o*3+2], gb = gb1[o];
    __shared__ float cs[16][12];
    for (int i = t; i < 16*9; i += 256) cs[i / 9][i % 9] = cosv[(size_t)(r0 + i/9)*9 + (i % 9)];
    __syncthreads();
    double s = 0.0, s2 = 0.0;
    for (int rr = sub; rr < 16; rr += 2) {
      int r = r0 + rr;
#pragma unroll
      for (int w = 0; w < 3; w++) {
        float acc = gb;
        acc += cs[rr][w*3+0]*g0;
        acc += cs[rr][w*3+1]*g1;
        acc += cs[rr][w*3+2]*g2;
        ANG[(size_t)r*384 + w*128 + o] = acc;
        s += (double)acc; s2 += (double)acc * (double)acc;
      }
    }
    __shared__ double ls[256], ls2[256];
    ls[t] = s; ls2[t] = s2;
    __syncthreads();
    if (sub == 0) {
      s += ls[128 + o]; s2 += ls2[128 + o];
      part2[((size_t)cbid*128 + o)*2] = s;
      part2[((size_t)cbid*128 + o)*2 + 1] = s2;
    }
  }
}

// ---------------- parallel stats final (f64 partials) ----------------
__global__ __launch_bounds__(256) void gm_final(const double* __restrict__ part, float* __restrict__ stats,
                                                int Cc, int NB, int nblk, int count) {
  int g = blockIdx.x * 8 + (threadIdx.x >> 5);
  int lane = threadIdx.x & 31;
  if (g >= NB*Cc) return;
  int b = g / Cc, o = g % Cc;
  double S = 0.0, S2 = 0.0;
  for (int u = lane; u < nblk; u += 32) {
    size_t blk = (size_t)(b*nblk + u);
    S  += part[(blk*Cc + o)*2];
    S2 += part[(blk*Cc + o)*2 + 1];
  }
  for (int off = 16; off >= 1; off >>= 1) {
    S  += __shfl_down(S, off, 32);
    S2 += __shfl_down(S2, off, 32);
  }
  if (lane == 0) {
    double mean = S / count;
    double var = S2 / count - mean*mean;
    if (var < 0.0) var = 0.0;
    stats[g*2] = (float)mean;
    stats[g*2 + 1] = (float)(1.0 / sqrt(var + 1e-5));
  }
}

// ---------------- parallel stats final (f32 partials, f64 accumulate) ----------------
__global__ __launch_bounds__(256) void gm_final_f(const float* __restrict__ part, float* __restrict__ stats,
                                                  int Cc, int NB, int nblk, int count) {
  int g = blockIdx.x * 8 + (threadIdx.x >> 5);
  int lane = threadIdx.x & 31;
  if (g >= NB*Cc) return;
  int b = g / Cc, o = g % Cc;
  double S = 0.0, S2 = 0.0;
  for (int u = lane; u < nblk; u += 32) {
    size_t blk = (size_t)(b*nblk + u);
    S  += (double)part[(blk*Cc + o)*2];
    S2 += (double)part[(blk*Cc + o)*2 + 1];
  }
  for (int off = 16; off >= 1; off >>= 1) {
    S  += __shfl_down(S, off, 32);
    S2 += __shfl_down(S2, off, 32);
  }
  if (lane == 0) {
    double mean = S / count;
    double var = S2 / count - mean*mean;
    if (var < 0.0) var = 0.0;
    stats[g*2] = (float)mean;
    stats[g*2 + 1] = (float)(1.0 / sqrt(var + 1e-5));
  }
}

// ---------------- gather + max over k + f64 partials (4 rows/block, idx in LDS) ----------------
__global__ __launch_bounds__(256) void gather_max_partial(const float* __restrict__ G, const int* __restrict__ idx,
                                                          float* __restrict__ maxbuf, double* __restrict__ part,
                                                          int Cc) {
  int t = threadIdx.x;
  int o = t % Cc, sub = t / Cc, nsub = 256 / Cc;
  int r0 = blockIdx.x * 4;
  __shared__ int nbs[4][9];
  if (t < 36) nbs[t / 9][t % 9] = idx[(size_t)(r0 + t/9)*9 + (t % 9)];
  __syncthreads();
  double s = 0.0, s2 = 0.0;
  for (int rr = sub; rr < 4; rr += nsub) {
    int r = r0 + rr, rb = r & ~2047;
    float g = G[(size_t)r*2*Cc + o];
    float mx = -3.4e38f;
#pragma unroll
    for (int k = 0; k < 9; k++) {
      int m = nbs[rr][k];
      float v = g + G[(size_t)(rb + m)*2*Cc + Cc + o];
      mx = fmaxf(mx, v); s += (double)v; s2 += (double)v*(double)v;
    }
    maxbuf[(size_t)r*Cc + o] = mx;
  }
  if (nsub == 2) {
    __shared__ double ls[256], ls2[256];
    ls[t] = s; ls2[t] = s2;
    __syncthreads();
    if (sub == 0) { s += ls[Cc + o]; s2 += ls2[Cc + o]; }
  }
  if (sub == 0) {
    part[((size_t)blockIdx.x*Cc + o)*2] = s;
    part[((size_t)blockIdx.x*Cc + o)*2 + 1] = s2;
  }
}

// ---------------- final: SA = lrelu(inorm(X3O)) + lrelu(inorm(X3A)) ----------------
__global__ void norm_add2(const float* __restrict__ src, float* __restrict__ dst,
                          const float* __restrict__ stats,
                          const float* __restrict__ addend, const float* __restrict__ astats,
                          int total) {
  int i = blockIdx.x * 256 + threadIdx.x;
  if (i >= total) return;
  int o = i & 127;
  int b = i >> 18;
  float m = stats[(b*128 + o)*2], rs = stats[(b*128 + o)*2 + 1];
  float v = (src[i] - m) * rs;
  v = (v >= 0.f) ? v : 0.2f*v;
  float ma = astats[(b*128 + o)*2], rsa = astats[(b*128 + o)*2 + 1];
  float a = (addend[i] - ma) * rsa;
  a = (a >= 0.f) ? a : 0.2f*a;
  dst[i] = v + a;
}

// ---------------- MFMA flash attention: bf16 Q/K/V inputs, 64 q-rows/block, split-K 8 ----------------
__global__ __launch_bounds__(256) void attn_part(const ushort* __restrict__ Qp, const ushort* __restrict__ Kp,
                                                 const ushort* __restrict__ Vp,
                                                 float* __restrict__ OP, float* __restrict__ ML) {
  __shared__ ushort Ks[64][40];   // K rows [key][dim], bf16
  __shared__ ushort Vt[32][72];   // V transposed [dim][key], bf16
  __shared__ ushort Pb[64][72];   // P rows [q-row][key 0..63], bf16 (front doubles as Q staging)
  int tid = threadIdx.x;
  int wv = tid >> 6, l = tid & 63;
  int d = l & 15, g = l >> 4;
  int kp = blockIdx.y, bh = blockIdx.z;
  int q0 = blockIdx.x * 64;
  const ushort* Qh = Qp + (size_t)bh * NPTS * 32;
  const ushort* Kh = Kp + (size_t)bh * NPTS * 32;
  const ushort* Vh = Vp + (size_t)bh * NPTS * 32;
  {
    int r = tid >> 2, c8 = (tid & 3) * 8;
    const ushort* q = Qh + (size_t)(q0 + r)*32 + c8;
    *(ushort4*)&Pb[r][c8]     = *(const ushort4*)q;
    *(ushort4*)&Pb[r][c8 + 4] = *(const ushort4*)(q + 4);
  }
  __syncthreads();
  bfrag qf = *(const bfrag*)&Pb[wv*16 + d][g*8];
  f32x4 Oc[2];
  Oc[0] = (f32x4){0.f,0.f,0.f,0.f}; Oc[1] = (f32x4){0.f,0.f,0.f,0.f};
  float m_[4] = {-FLT_MAX, -FLT_MAX, -FLT_MAX, -FLT_MAX};
  float l_[4] = {0.f, 0.f, 0.f, 0.f};
  const float sc = 0.17677669529663687f;   // 1/sqrt(32)
  int ks0 = kp * (NPTS / SPLITK);
  for (int k0 = ks0; k0 < ks0 + NPTS/SPLITK; k0 += 64) {
    __syncthreads();
    {
      int r = tid >> 2, c8 = (tid & 3) * 8;
      const ushort* kr = Kh + (size_t)(k0 + r)*32 + c8;
      *(ushort4*)&Ks[r][c8]     = *(const ushort4*)kr;
      *(ushort4*)&Ks[r][c8 + 4] = *(const ushort4*)(kr + 4);
      int vr = tid & 63, vd = (tid >> 6) * 8;
      const ushort* vp = Vh + (size_t)(k0 + vr)*32 + vd;
      ushort4 b0 = *(const ushort4*)vp, b1 = *(const ushort4*)(vp + 4);
      Vt[vd+0][vr] = b0.x; Vt[vd+1][vr] = b0.y;
      Vt[vd+2][vr] = b0.z; Vt[vd+3][vr] = b0.w;
      Vt[vd+4][vr] = b1.x; Vt[vd+5][vr] = b1.y;
      Vt[vd+6][vr] = b1.z; Vt[vd+7][vr] = b1.w;
    }
    __syncthreads();
    f32x4 S[4];
#pragma unroll
    for (int c = 0; c < 4; c++) {
      S[c] = (f32x4){0.f,0.f,0.f,0.f};
      bfrag kf = *(const bfrag*)&Ks[c*16 + d][g*8];
      S[c] = __builtin_amdgcn_mfma_f32_16x16x32_bf16(qf, kf, S[c], 0, 0, 0);
    }
    float cf[4];
#pragma unroll
    for (int i = 0; i < 4; i++) {
      float tm = fmaxf(fmaxf(S[0][i], S[1][i]), fmaxf(S[2][i], S[3][i])) * sc;
      for (int off = 1; off < 16; off <<= 1) tm = fmaxf(tm, __shfl_xor(tm, off));
      float mn = fmaxf(m_[i], tm);
      cf[i] = __expf(m_[i] - mn);
      m_[i] = mn;
    }
    float rs[4] = {0.f, 0.f, 0.f, 0.f};
    ushort pu[4][4];
#pragma unroll
    for (int c = 0; c < 4; c++)
#pragma unroll
      for (int i = 0; i < 4; i++) {
        float p = __expf(fmaf(S[c][i], sc, -m_[i]));
        rs[i] += p;
        pu[c][i] = f2bf(p);
      }
#pragma unroll
    for (int i = 0; i < 4; i++) {
      float r2 = rs[i];
      for (int off = 1; off < 16; off <<= 1) r2 += __shfl_xor(r2, off);
      l_[i] = l_[i]*cf[i] + r2;
      Oc[0][i] *= cf[i]; Oc[1][i] *= cf[i];
    }
#pragma unroll
    for (int c = 0; c < 4; c++)
#pragma unroll
      for (int i = 0; i < 4; i++)
        Pb[wv*16 + g*4 + i][c*16 + d] = pu[c][i];
#pragma unroll
    for (int s5 = 0; s5 < 2; s5++) {
      bfrag pf = *(const bfrag*)&Pb[wv*16 + d][g*8 + 32*s5];
#pragma unroll
      for (int td = 0; td < 2; td++) {
        union { ushort4 v4[2]; bfrag f; } vu;
        vu.v4[0] = *(const ushort4*)&Vt[td*16 + d][g*8 + 32*s5];
        vu.v4[1] = *(const ushort4*)&Vt[td*16 + d][g*8 + 32*s5 + 4];
        Oc[td] = __builtin_amdgcn_mfma_f32_16x16x32_bf16(pf, vu.f, Oc[td], 0, 0, 0);
      }
    }
  }
  size_t pb = (size_t)(kp*8 + bh) * NPTS;
#pragma unroll
  for (int i = 0; i < 4; i++) {
    int n = q0 + wv*16 + g*4 + i;
    OP[(pb + n)*32 + d]      = Oc[0][i];
    OP[(pb + n)*32 + 16 + d] = Oc[1][i];
    if (d == 0) { ML[(pb + n)*2] = m_[i]; ML[(pb + n)*2 + 1] = l_[i]; }
  }
}

// ---------------- merge the eight K-slices ----------------
__global__ void attn_merge(const float* __restrict__ OP, const float* __restrict__ ML,
                           float* __restrict__ out) {
  int i = blockIdx.x * 256 + threadIdx.x;   // 8*2048*16
  if (i >= 8*2048*16) return;
  int dp = (i & 15) * 2;
  int n  = (i >> 4) & 2047;
  int bh = i >> 15;
  float mv[SPLITK], lv[SPLITK];
  float mm = -FLT_MAX;
#pragma unroll
  for (int p = 0; p < SPLITK; p++) {
    size_t pp = ((size_t)(p*8 + bh) * NPTS + n);
    mv[p] = ML[pp*2]; lv[p] = ML[pp*2 + 1];
    mm = fmaxf(mm, mv[p]);
  }
  float L = 0.f, ox = 0.f, oy = 0.f;
#pragma unroll
  for (int p = 0; p < SPLITK; p++) {
    size_t pp = ((size_t)(p*8 + bh) * NPTS + n);
    float w = __expf(mv[p] - mm);
    L += w * lv[p];
    float2 o = *(const float2*)&OP[pp*32 + dp];
    ox += w * o.x; oy += w * o.y;
  }
  float inv = 1.f / L;
  int b = bh >> 2, h = bh & 3;
  out[((size_t)(b*NPTS + n))*128 + (dp+0)*4 + h] = ox * inv;
  out[((size_t)(b*NPTS + n))*128 + (dp+1)*4 + h] = oy * inv;
}

// ================= host =================
extern "C" void kernel_launch(void* const* d_in, const int* in_sizes, int n_in,
                              void* d_out, int out_size, void* d_ws, size_t ws_size,
                              hipStream_t stream) {
  (void)in_sizes; (void)n_in; (void)out_size; (void)ws_size;
  const float* desc0  = (const float*)d_in[0];
  const float* desc1  = (const float*)d_in[1];
  const float* coords0= (const float*)d_in[2];
  const float* coords1= (const float*)d_in[3];
  const float* conv1w = (const float*)d_in[4];
  const float* conv2w = (const float*)d_in[5];
  const float* conv3w = (const float*)d_in[6];
  const float* conv3ow= (const float*)d_in[7];
  const float* a1w1 = (const float*)d_in[8];
  const float* a1b1 = (const float*)d_in[9];
  const float* a1w2 = (const float*)d_in[10];
  const float* a1b2 = (const float*)d_in[11];
  const float* a2w1 = (const float*)d_in[12];
  const float* a2b1 = (const float*)d_in[13];
  const float* a2w2 = (const float*)d_in[14];
  const float* a2b2 = (const float*)d_in[15];
  const float* gw1  = (const float*)d_in[16];
  const float* gb1  = (const float*)d_in[17];
  const float* gw2  = (const float*)d_in[18];
  const float* gb2  = (const float*)d_in[19];
  const float* wq = (const float*)d_in[20]; const float* bq = (const float*)d_in[21];
  const float* wk = (const float*)d_in[22]; const float* bk = (const float*)d_in[23];
  const float* wv = (const float*)d_in[24]; const float* bv = (const float*)d_in[25];
  const float* wm = (const float*)d_in[26]; const float* bm = (const float*)d_in[27];
  const float* mw1 = (const float*)d_in[28]; const float* mb1 = (const float*)d_in[29];
  const float* mw2 = (const float*)d_in[30]; const float* mb2 = (const float*)d_in[31];

  float* ws = (float*)d_ws;
  size_t off = 0;
  auto alloc = [&](size_t nel) { size_t r = off; off += (nel + 63) & ~(size_t)63; return r; };
  // bf16 weight buffers (elems/2 floats each)
  ushort* DW_A1 = (ushort*)(ws + alloc(512*128/2));
  ushort* W_A1R = (ushort*)(ws + alloc(128*384/2));
  ushort* DW_A2 = (ushort*)(ws + alloc(512*128/2));
  ushort* W_A2R = (ushort*)(ws + alloc(128*384/2));
  ushort* W_G2R = (ushort*)(ws + alloc(128*384/2));
  ushort* DW_C1 = (ushort*)(ws + alloc(256*128/2));
  ushort* DW_C2 = (ushort*)(ws + alloc(512*128/2));
  ushort* W_KV  = (ushort*)(ws + alloc(256*128/2));
  ushort* WB_C3 = (ushort*)(ws + alloc(128*384/2));
  ushort* WB_C3O= (ushort*)(ws + alloc(128*512/2));
  ushort* WB_Q  = (ushort*)(ws + alloc(128*128/2));
  ushort* WB_M  = (ushort*)(ws + alloc(128*128/2));
  ushort* WB_M1 = (ushort*)(ws + alloc(256*256/2));
  ushort* WB_M2 = (ushort*)(ws + alloc(128*256/2));
  float* B_KV  = ws + alloc(256);
  float* SA   = ws + alloc((size_t)R2*128);   // SA0 rows 0..4095 | SA1 rows 4096..8191
  float* XF0  = ws + alloc((size_t)4096*128); // contiguous with XF1 for fused z=4 transpose
  float* XF1  = ws + alloc((size_t)4096*128);
  int*   IDX  = (int*)(ws + alloc((size_t)R2*9));
  float* COSV = ws + alloc((size_t)R2*9);
  ushort* FT  = (ushort*)(ws + alloc((size_t)R2*128/2));  // bf16 at rest
  float* BIG  = ws + alloc((size_t)R2*512);
  float* ABUF = ws + alloc((size_t)R2*384);
  float* X1B  = ws + alloc((size_t)R2*128);
  float* FANG = ws + alloc((size_t)R2*128);
  float* X2B  = ws + alloc((size_t)R2*128);
  float* X3A  = ws + alloc((size_t)R2*128);
  float* X1O  = ws + alloc((size_t)R2*128);
  float* AB2  = ws + alloc((size_t)R2*256);
  float* X3O  = ws + alloc((size_t)R2*128);
  double* PART = (double*)(ws + alloc((size_t)2048*256*2*2));   // 1M doubles (8 MB)
  float*  PARTF = (float*)PART;                                  // aliased f32 partials
  double* PART2 = PART + (size_t)512*1024;                       // disjoint region for cos stats
  float* STATS = ws + alloc(8*2048);
  float* MLB  = ws + alloc((size_t)SPLITK*8*NPTS*2);            // attn m/l partials
  float* ST_T   = STATS;
  float* ST_X1B = STATS + 2048;
  float* ST_FANG= STATS + 4096;
  float* ST_X2B = STATS + 6144;
  float* ST_X3A = STATS + 8192;
  float* ST_X1O = STATS + 10240;
  float* ST_AB  = STATS + 12288;
  float* ST_X3O = STATS + 14336;
  float* OP  = BIG;    // attn O partials: SPLITK*8*2048*32 = R2*512 floats exactly

  auto g64 = [&](const float* p0,int w0,const float* st0,int a0,int x0,int xbf,
                 const float* p1,int w1,const float* st1,int a1,int x1,
                 const float* p2,int w2,const float* st2,int a2,int x2,
                 const float* addp,const float* addst,
                 const ushort* W,const float* bias,const float* resid,
                 float* Y,int R,int Cin,int O,int pack,float* Y2,float* part) {
    gemm_m<64><<<dim3(R/64, O/64), 256, 0, stream>>>(p0,w0,st0,a0,x0,xbf, p1,w1,st1,a1,x1,
        p2,w2,st2,a2,x2, addp,addst, W,bias,resid, Y,Cin,O,pack,Y2,part);
  };
  auto g32 = [&](const float* p0,int w0,const float* st0,int a0,int x0,int xbf,
                 const float* p1,int w1,const float* st1,int a1,int x1,
                 const float* p2,int w2,const float* st2,int a2,int x2,
                 const float* addp,const float* addst,
                 const ushort* W,const float* bias,const float* resid,
                 float* Y,int R,int Cin,int O,int pack,float* Y2,float* part) {
    gemm_m<32><<<dim3(R/32, O/64), 256, 0, stream>>>(p0,w0,st0,a0,x0,xbf, p1,w1,st1,a1,x1,
        p2,w2,st2,a2,x2, addp,addst, W,bias,resid, Y,Cin,O,pack,Y2,part);
  };
  auto statsF = [&](float* stat, int O, int NB, int nblk, int count) {
    gm_final_f<<<(NB*O + 7)/8, 256, 0, stream>>>(PARTF, stat, O, NB, nblk, count);
  };
  auto statsD = [&](float* stat, int O, int NB, int nblk, int count) {
    gm_final<<<(NB*O + 7)/8, 256, 0, stream>>>(PART, stat, O, NB, nblk, count);
  };
  auto gathermax = [&](const float* G, float* mx, int Cc, float* stat) {
    gather_max_partial<<<R2/4, 256, 0, stream>>>(G, IDX, mx, PART, Cc);
    statsD(stat, Cc, 4, 512, 2048*9);
  };

  // ===== fused prologue: prep_weights(+bf16) + transpose2(bf16) + knn =====
  prologue<<<3328, 256, 0, stream>>>(conv1w, conv2w, conv3w, conv3ow,
                                     a1w1, a1w2, a2w1, a2w2, gw2,
                                     wk, bk, wv, bv, wq, wm, mw1, mw2,
                                     DW_A1, W_A1R, DW_A2, W_A2R, W_G2R, DW_C1, DW_C2,
                                     W_KV, B_KV,
                                     WB_C3, WB_C3O, WB_Q, WB_M, WB_M1, WB_M2,
                                     desc0, desc1, FT,
                                     coords0, coords1, IDX, COSV);

  const float* FTf = (const float*)FT;   // bf16 buffer passed via xbf=1

  // ===== merged branch section (both descs, R2 = 8192 rows, 4 instances) =====
  // annu1
  g64(FTf,128,nullptr,0,0,1, nullptr,0,nullptr,0,0, nullptr,0,nullptr,0,0, nullptr,nullptr,
      DW_A1, nullptr, nullptr, BIG, R2, 128, 512, 0, nullptr, nullptr);
  combine_annu<<<R2/4, 256, 0, stream>>>(BIG, IDX, a1b1, ABUF, PART);
  statsD(ST_T, 128, 4, 512, 2048*3);
  g32(ABUF,384,ST_T,1,128,0, nullptr,0,nullptr,0,0, nullptr,0,nullptr,0,0, nullptr,nullptr,
      W_A1R, a1b2, nullptr, X1B, R2, 384, 128, 0, nullptr, PARTF);
  // fused: statsF(ST_X1B) || cos_conv (f_ang conv1; writes PART2)
  stats_cos<<<64 + R2/16, 256, 0, stream>>>(PARTF, ST_X1B, COSV, gw1, gb1, ABUF, PART2);
  gm_final<<<(4*128 + 7)/8, 256, 0, stream>>>(PART2, ST_T, 128, 4, 128, 2048*3);
  g32(ABUF,384,ST_T,1,128,0, nullptr,0,nullptr,0,0, nullptr,0,nullptr,0,0, nullptr,nullptr,
      W_G2R, gb2, nullptr, FANG, R2, 384, 128, 0, nullptr, PARTF);
  statsF(ST_FANG, 128, 4, 64, 2048);
  // annu2 (X1B raw, normed in staging)
  g64(X1B,128,ST_X1B,1,128,0, nullptr,0,nullptr,0,0, nullptr,0,nullptr,0,0, nullptr,nullptr,
      DW_A2, nullptr, nullptr, BIG, R2, 128, 512, 0, nullptr, nullptr);
  combine_annu<<<R2/4, 256, 0, stream>>>(BIG, IDX, a2b1, ABUF, PART);
  statsD(ST_T, 128, 4, 512, 2048*3);
  g32(ABUF,384,ST_T,1,128,0, nullptr,0,nullptr,0,0, nullptr,0,nullptr,0,0, nullptr,nullptr,
      W_A2R, a2b2, nullptr, X2B, R2, 384, 128, 0, nullptr, PARTF);
  statsF(ST_X2B, 128, 4, 64, 2048);
  // x3 = conv3 @ [x0 | n(x1)+n(fang) | n(x2)+n(fang)]
  g32(FTf,128,nullptr,0,0,1, X1B,128,ST_X1B,1,128, X2B,128,ST_X2B,1,128, FANG,ST_FANG,
      WB_C3, nullptr, nullptr, X3A, R2, 384, 128, 0, nullptr, PARTF);
  statsF(ST_X3A, 128, 4, 64, 2048);
  // x1o
  g64(FTf,128,nullptr,0,0,1, nullptr,0,nullptr,0,0, nullptr,0,nullptr,0,0, nullptr,nullptr,
      DW_C1, nullptr, nullptr, BIG, R2, 128, 256, 0, nullptr, nullptr);
  gathermax(BIG, X1O, 128, ST_X1O);
  // x2o (X1O = raw max, normed lrelu in staging)
  g64(X1O,128,ST_X1O,2,128,0, nullptr,0,nullptr,0,0, nullptr,0,nullptr,0,0, nullptr,nullptr,
      DW_C2, nullptr, nullptr, BIG, R2, 128, 512, 0, nullptr, nullptr);
  gathermax(BIG, AB2, 256, ST_AB);
  // x3o = conv3o @ [x0 | n(x1o) | n(x2o)]
  g32(FTf,128,nullptr,0,0,1, X1O,128,ST_X1O,2,128, AB2,256,ST_AB,2,256, nullptr,nullptr,
      WB_C3O, nullptr, nullptr, X3O, R2, 512, 128, 0, nullptr, PARTF);
  statsF(ST_X3O, 128, 4, 64, 2048);
  norm_add2<<<(R2*128 + 255)/256, 256, 0, stream>>>(X3O, SA, ST_X3O, X3A, ST_X3A, R2*128);

  // ===== cross-attention props (rows 4096 each) =====
  float* SA1 = SA + (size_t)4096*128;
  auto prop = [&](const float* xbase, float* dst) {
    const float* xin = xbase;
    gemm_qkv<<<dim3(256, 4), 256, 0, stream>>>(xbase, WB_Q, bq, X1B, W_KV, B_KV, X2B, X3A);
    attn_part<<<dim3(2048/64, SPLITK, 8), 256, 0, stream>>>(
        (const ushort*)X1B, (const ushort*)X2B, (const ushort*)X3A, OP, MLB);
    attn_merge<<<(8*2048*16 + 255)/256, 256, 0, stream>>>(OP, MLB, FANG);
    g32(FANG,128,nullptr,0,0,0, nullptr,0,nullptr,0,0, nullptr,0,nullptr,0,0, nullptr,nullptr,
        WB_M, bm, nullptr, X1O, 4096, 128, 128, 0, nullptr, nullptr);
    g32(xin,128,nullptr,0,0,0, X1O,128,nullptr,0,0, nullptr,0,nullptr,0,0, nullptr,nullptr,
        WB_M1, mb1, nullptr, ABUF, 4096, 256, 256, 0, nullptr, PARTF);
    statsF(ST_T, 256, 2, 64, 2048);
    g32(ABUF,256,ST_T,1,256,0, nullptr,0,nullptr,0,0, nullptr,0,nullptr,0,0, nullptr,nullptr,
        WB_M2, mb2, xin, dst, 4096, 256, 128, 0, nullptr, nullptr);
  };

  prop(SA, XF0);
  prop(SA1, XF1);

  transpose_k<<<dim3(128/32, 2048/32, 4), dim3(32, 8), 0, stream>>>(XF0, (float*)d_out, 2048, 128);
}